// Round 1
// baseline (4415.339 us; speedup 1.0000x reference)
//
#include <hip/hip_runtime.h>
#include <math.h>

#define EPSV 1e-5f

// ---------------------------------------------------------------- input proj
// h[n,f] = relu(sum_k x[n,k]*W[k,f] + b[f]),  x:[N,14], W:[14,128]
__global__ void k_proj(const float* __restrict__ x, const float* __restrict__ W,
                       const float* __restrict__ b, float* __restrict__ h, int nN) {
  int gid = blockIdx.x * 256 + threadIdx.x;
  if (gid >= nN * 128) return;
  int n = gid >> 7, f = gid & 127;
  const float* xr = x + n * 14;
  float acc = b[f];
#pragma unroll
  for (int k = 0; k < 14; ++k) acc = fmaf(xr[k], W[k * 128 + f], acc);
  h[gid] = fmaxf(acc, 0.f);
}

// ---------------------------------------------------------------- degree count
__global__ void k_count(const int* __restrict__ dst, float* __restrict__ cnt, int E_) {
  int e = blockIdx.x * 256 + threadIdx.x;
  if (e < E_) atomicAdd(&cnt[dst[e]], 1.0f);
}

// ---------------------------------------------------------------- SAGE scatter
// s[dst] += h[src], 32 threads/edge, float4 per thread
__global__ void k_scatter(const float4* __restrict__ h4, const int* __restrict__ src,
                          const int* __restrict__ dst, float* __restrict__ s, int E_) {
  int t = blockIdx.x * 256 + threadIdx.x;
  int e = t >> 5;
  if (e >= E_) return;
  int lane = t & 31;
  int sN = src[e], dN = dst[e];
  float4 v = h4[(size_t)sN * 32 + lane];
  float* sp = s + (size_t)dN * 128 + lane * 4;
  atomicAdd(sp + 0, v.x);
  atomicAdd(sp + 1, v.y);
  atomicAdd(sp + 2, v.z);
  atomicAdd(sp + 3, v.w);
}

// ---------------------------------------------------------------- fused SAGE layer
// Hout = relu(LN( [S/cnt | Hin] @ [Wl;Wr] + bias )) + Hin
// block: 256 thr, 64 rows x 128 cols, K=256 in BK=32 tiles
__global__ __launch_bounds__(256)
void k_sage(const float* __restrict__ S, const float* __restrict__ cnt,
            const float* __restrict__ Hin, const float* __restrict__ Wl,
            const float* __restrict__ Wr, const float* __restrict__ bias,
            const float* __restrict__ gam, const float* __restrict__ bet,
            float* __restrict__ Hout, int nN) {
  __shared__ float As[32][65];
  __shared__ float Bs[32][128];
  int tid = threadIdx.x;
  int tx = tid & 31, ty = tid >> 5;
  int rowBase = blockIdx.x * 64;
  float acc[8][4];
#pragma unroll
  for (int i = 0; i < 8; ++i)
#pragma unroll
    for (int j = 0; j < 4; ++j) acc[i][j] = 0.f;

  int lm = tid >> 2;           // 0..63  (tile row)
  int lk = (tid & 3) * 8;      // 0,8,16,24
  int bkr = tid >> 3;          // 0..31
  int bcq = (tid & 7) * 16;    // 0..112

  for (int k0 = 0; k0 < 256; k0 += 32) {
    int grow = rowBase + lm;
    if (grow < nN) {
      if (k0 < 128) {
        float invc = 1.0f / fmaxf(cnt[grow], 1.0f);
        const float* p = S + (size_t)grow * 128 + k0 + lk;
#pragma unroll
        for (int u = 0; u < 8; ++u) As[lk + u][lm] = p[u] * invc;
      } else {
        const float* p = Hin + (size_t)grow * 128 + (k0 - 128) + lk;
#pragma unroll
        for (int u = 0; u < 8; ++u) As[lk + u][lm] = p[u];
      }
    } else {
#pragma unroll
      for (int u = 0; u < 8; ++u) As[lk + u][lm] = 0.f;
    }
    {
      int gk = k0 + bkr;
      const float* bp = (gk < 128) ? (Wl + (size_t)gk * 128 + bcq)
                                   : (Wr + (size_t)(gk - 128) * 128 + bcq);
#pragma unroll
      for (int u = 0; u < 4; ++u) {
        float4 v = *(const float4*)(bp + 4 * u);
        *(float4*)&Bs[bkr][bcq + 4 * u] = v;
      }
    }
    __syncthreads();
#pragma unroll
    for (int kk = 0; kk < 32; ++kk) {
      float b0 = Bs[kk][tx], b1 = Bs[kk][tx + 32], b2 = Bs[kk][tx + 64], b3 = Bs[kk][tx + 96];
#pragma unroll
      for (int i = 0; i < 8; ++i) {
        float a = As[kk][ty + 8 * i];
        acc[i][0] = fmaf(a, b0, acc[i][0]);
        acc[i][1] = fmaf(a, b1, acc[i][1]);
        acc[i][2] = fmaf(a, b2, acc[i][2]);
        acc[i][3] = fmaf(a, b3, acc[i][3]);
      }
    }
    __syncthreads();
  }

  float bi0 = bias[tx], bi1 = bias[tx + 32], bi2 = bias[tx + 64], bi3 = bias[tx + 96];
  float g0 = gam[tx], g1 = gam[tx + 32], g2 = gam[tx + 64], g3v = gam[tx + 96];
  float e0 = bet[tx], e1 = bet[tx + 32], e2 = bet[tx + 64], e3 = bet[tx + 96];
#pragma unroll
  for (int i = 0; i < 8; ++i) {
    int grow = rowBase + ty + 8 * i;
    float v0 = acc[i][0] + bi0, v1 = acc[i][1] + bi1, v2 = acc[i][2] + bi2, v3 = acc[i][3] + bi3;
    float s1 = v0 + v1 + v2 + v3;
    float s2 = v0 * v0 + v1 * v1 + v2 * v2 + v3 * v3;
#pragma unroll
    for (int m = 16; m >= 1; m >>= 1) { s1 += __shfl_xor(s1, m); s2 += __shfl_xor(s2, m); }
    float mean = s1 * (1.f / 128.f);
    float var = s2 * (1.f / 128.f) - mean * mean;
    float rstd = rsqrtf(var + EPSV);
    if (grow < nN) {
      const float* res = Hin + (size_t)grow * 128;
      float* o = Hout + (size_t)grow * 128;
      o[tx]      = fmaxf((v0 - mean) * rstd * g0 + e0, 0.f) + res[tx];
      o[tx + 32] = fmaxf((v1 - mean) * rstd * g1 + e1, 0.f) + res[tx + 32];
      o[tx + 64] = fmaxf((v2 - mean) * rstd * g2 + e2, 0.f) + res[tx + 64];
      o[tx + 96] = fmaxf((v3 - mean) * rstd * g3v + e3, 0.f) + res[tx + 96];
    }
  }
}

// ---------------------------------------------------------------- GAT GEMM
// G[N,256] = A[N,128] @ Wg[128,256]
__global__ __launch_bounds__(256)
void k_gemm_gat(const float* __restrict__ A, const float* __restrict__ Wg,
                float* __restrict__ G, int nN) {
  __shared__ float As[32][65];
  __shared__ float Bs[32][256];
  int tid = threadIdx.x;
  int tx = tid & 31, ty = tid >> 5;
  int rowBase = blockIdx.x * 64;
  float acc[8][8];
#pragma unroll
  for (int i = 0; i < 8; ++i)
#pragma unroll
    for (int j = 0; j < 8; ++j) acc[i][j] = 0.f;

  int lm = tid >> 2, lk = (tid & 3) * 8;
  int bkr = tid >> 3, bcq = (tid & 7) * 32;

  for (int k0 = 0; k0 < 128; k0 += 32) {
    int grow = rowBase + lm;
    if (grow < nN) {
      const float* p = A + (size_t)grow * 128 + k0 + lk;
#pragma unroll
      for (int u = 0; u < 8; ++u) As[lk + u][lm] = p[u];
    } else {
#pragma unroll
      for (int u = 0; u < 8; ++u) As[lk + u][lm] = 0.f;
    }
    {
      const float* bp = Wg + (size_t)(k0 + bkr) * 256 + bcq;
#pragma unroll
      for (int u = 0; u < 8; ++u) {
        float4 v = *(const float4*)(bp + 4 * u);
        *(float4*)&Bs[bkr][bcq + 4 * u] = v;
      }
    }
    __syncthreads();
#pragma unroll
    for (int kk = 0; kk < 32; ++kk) {
      float br[8];
#pragma unroll
      for (int j = 0; j < 8; ++j) br[j] = Bs[kk][tx + 32 * j];
#pragma unroll
      for (int i = 0; i < 8; ++i) {
        float a = As[kk][ty + 8 * i];
#pragma unroll
        for (int j = 0; j < 8; ++j) acc[i][j] = fmaf(a, br[j], acc[i][j]);
      }
    }
    __syncthreads();
  }
#pragma unroll
  for (int i = 0; i < 8; ++i) {
    int grow = rowBase + ty + 8 * i;
    if (grow < nN) {
      float* o = G + (size_t)grow * 256;
#pragma unroll
      for (int j = 0; j < 8; ++j) o[tx + 32 * j] = acc[i][j];
    }
  }
}

// ---------------------------------------------------------------- attention logits
// as_[n,h] = sum_f G[n,h*64+f]*att_src[h,f]  (one 64-lane wave per node)
__global__ void k_att(const float* __restrict__ G, const float* __restrict__ att_src,
                      const float* __restrict__ att_dst, float* __restrict__ as_,
                      float* __restrict__ ad_, int nN) {
  int t = blockIdx.x * 256 + threadIdx.x;
  int n = t >> 6, lane = t & 63;
  if (n >= nN) return;
  const float* g = G + (size_t)n * 256;
#pragma unroll
  for (int h = 0; h < 4; ++h) {
    float v = g[h * 64 + lane];
    float ps = v * att_src[h * 64 + lane];
    float pd = v * att_dst[h * 64 + lane];
#pragma unroll
    for (int m = 32; m >= 1; m >>= 1) { ps += __shfl_xor(ps, m); pd += __shfl_xor(pd, m); }
    if (lane == 0) { as_[n * 4 + h] = ps; ad_[n * 4 + h] = pd; }
  }
}

// ---------------------------------------------------------------- GAT self-loop init
// acc[n,c] = w(n,head(c)) * G[n,c];  den[n,h] = w(n,h)   (single writer)
__global__ void k_gat_self(const float* __restrict__ G, const float* __restrict__ as_,
                           const float* __restrict__ ad_, float* __restrict__ acc,
                           float* __restrict__ den, int nN) {
  int n = blockIdx.x;
  int c = threadIdx.x;
  if (n >= nN) return;
  int h = c >> 6;
  float e = as_[n * 4 + h] + ad_[n * 4 + h];
  e = e > 0.f ? e : 0.2f * e;
  float w = expf(e);
  acc[(size_t)n * 256 + c] = w * G[(size_t)n * 256 + c];
  if (c < 4) {
    float e2 = as_[n * 4 + c] + ad_[n * 4 + c];
    e2 = e2 > 0.f ? e2 : 0.2f * e2;
    den[n * 4 + c] = expf(e2);
  }
}

// ---------------------------------------------------------------- GAT edge scatter
// 64 threads/edge: w[h]=exp(leaky(as[src,h]+ad[dst,h])); acc[dst]+=w*G[src]; den[dst]+=w
__global__ void k_gat_scatter(const float4* __restrict__ G4, const int* __restrict__ src,
                              const int* __restrict__ dst, const float* __restrict__ as_,
                              const float* __restrict__ ad_, float* __restrict__ acc,
                              float* __restrict__ den, int E_) {
  int t = blockIdx.x * 256 + threadIdx.x;
  int e = t >> 6;
  if (e >= E_) return;
  int lane = t & 63;
  int sN = src[e], dN = dst[e];
  int h = lane >> 4;
  float ev = as_[sN * 4 + h] + ad_[dN * 4 + h];
  ev = ev > 0.f ? ev : 0.2f * ev;
  float w = expf(ev);
  if (lane < 4) {
    float e2 = as_[sN * 4 + lane] + ad_[dN * 4 + lane];
    e2 = e2 > 0.f ? e2 : 0.2f * e2;
    atomicAdd(&den[dN * 4 + lane], expf(e2));
  }
  float4 v = G4[(size_t)sN * 64 + lane];
  float* ap = acc + (size_t)dN * 256 + lane * 4;
  atomicAdd(ap + 0, w * v.x);
  atomicAdd(ap + 1, w * v.y);
  atomicAdd(ap + 2, w * v.z);
  atomicAdd(ap + 3, w * v.w);
}

// ---------------------------------------------------------------- GAT finalize + LN
// out[n,f] = LN_f( mean_h(acc[n,h,f]/den[n,h]) + bg[f] ) * g3 + be3
__global__ void k_gat_final(const float* __restrict__ acc, const float* __restrict__ den,
                            const float* __restrict__ bg, const float* __restrict__ g3,
                            const float* __restrict__ be3, float* __restrict__ out, int nN) {
  int t = blockIdx.x * 256 + threadIdx.x;
  int n = t >> 6, f = t & 63;
  if (n >= nN) return;
  float v = 0.f;
#pragma unroll
  for (int h = 0; h < 4; ++h) v += acc[(size_t)n * 256 + h * 64 + f] / den[n * 4 + h];
  v = v * 0.25f + bg[f];
  float s1 = v, s2 = v * v;
#pragma unroll
  for (int m = 32; m >= 1; m >>= 1) { s1 += __shfl_xor(s1, m); s2 += __shfl_xor(s2, m); }
  float mean = s1 * (1.f / 64.f);
  float var = s2 * (1.f / 64.f) - mean * mean;
  float rstd = rsqrtf(var + EPSV);
  out[(size_t)n * 64 + f] = (v - mean) * rstd * g3[f] + be3[f];
}

// ================================================================ launch
extern "C" void kernel_launch(void* const* d_in, const int* in_sizes, int n_in,
                              void* d_out, int out_size, void* d_ws, size_t ws_size,
                              hipStream_t stream) {
  const float* x    = (const float*)d_in[0];
  const int*   edge = (const int*)d_in[1];
  const float* W_in = (const float*)d_in[2];
  const float* b_in = (const float*)d_in[3];
  const float* W1_l = (const float*)d_in[4];
  const float* b1   = (const float*)d_in[5];
  const float* W1_r = (const float*)d_in[6];
  const float* g1   = (const float*)d_in[7];
  const float* be1  = (const float*)d_in[8];
  const float* W2_l = (const float*)d_in[9];
  const float* b2   = (const float*)d_in[10];
  const float* W2_r = (const float*)d_in[11];
  const float* g2   = (const float*)d_in[12];
  const float* be2  = (const float*)d_in[13];
  const float* W_g  = (const float*)d_in[14];
  const float* atts = (const float*)d_in[15];
  const float* attd = (const float*)d_in[16];
  const float* b_g  = (const float*)d_in[17];
  const float* g3   = (const float*)d_in[18];
  const float* be3  = (const float*)d_in[19];

  const int nN = in_sizes[0] / 14;
  const int E_ = in_sizes[1] / 2;
  const int* src = edge;
  const int* dst = edge + E_;

  float* WS  = (float*)d_ws;
  float* Sb  = WS;                          // N*128  (low half of ACC)
  float* Bb  = WS + (size_t)nN * 128;       // N*128  (high half of ACC)
  float* Ab  = WS + (size_t)nN * 256;       // N*128
  float* Gb  = WS + (size_t)nN * 384;       // N*256
  float* CNT = WS + (size_t)nN * 640;       // N
  float* AS_ = CNT + nN;                    // N*4
  float* AD_ = AS_ + (size_t)nN * 4;        // N*4
  float* DEN = AD_ + (size_t)nN * 4;        // N*4
  float* ACC = Sb;                          // N*256 (spans Sb..Bb)

  hipMemsetAsync(CNT, 0, (size_t)nN * sizeof(float), stream);
  hipMemsetAsync(Sb, 0, (size_t)nN * 128 * sizeof(float), stream);

  // input projection -> Ab (h0)
  k_proj<<<(nN * 128 + 255) / 256, 256, 0, stream>>>(x, W_in, b_in, Ab, nN);
  k_count<<<(E_ + 255) / 256, 256, 0, stream>>>(dst, CNT, E_);

  // SAGE layer 1: Ab -> Bb
  k_scatter<<<(E_ * 32 + 255) / 256, 256, 0, stream>>>((const float4*)Ab, src, dst, Sb, E_);
  k_sage<<<(nN + 63) / 64, 256, 0, stream>>>(Sb, CNT, Ab, W1_l, W1_r, b1, g1, be1, Bb, nN);

  // SAGE layer 2: Bb -> Ab
  hipMemsetAsync(Sb, 0, (size_t)nN * 128 * sizeof(float), stream);
  k_scatter<<<(E_ * 32 + 255) / 256, 256, 0, stream>>>((const float4*)Bb, src, dst, Sb, E_);
  k_sage<<<(nN + 63) / 64, 256, 0, stream>>>(Sb, CNT, Bb, W2_l, W2_r, b2, g2, be2, Ab, nN);

  // GAT: Ab -> Gb -> out
  k_gemm_gat<<<(nN + 63) / 64, 256, 0, stream>>>(Ab, W_g, Gb, nN);
  k_att<<<(nN * 64 + 255) / 256, 256, 0, stream>>>(Gb, atts, attd, AS_, AD_, nN);
  k_gat_self<<<nN, 256, 0, stream>>>(Gb, AS_, AD_, ACC, DEN, nN);
  k_gat_scatter<<<(E_ * 64 + 255) / 256, 256, 0, stream>>>((const float4*)Gb, src, dst, AS_, AD_, ACC, DEN, E_);
  k_gat_final<<<(nN * 64 + 255) / 256, 256, 0, stream>>>(ACC, DEN, b_g, g3, be3, (float*)d_out, nN);
}

// Round 3
// 564.408 us; speedup vs baseline: 7.8229x; 7.8229x over previous
//
#include <hip/hip_runtime.h>
#include <math.h>

#define EPSV 1e-5f

// ---------------------------------------------------------------- input proj
// h[n,f] = relu(sum_k x[n,k]*W[k,f] + b[f]),  x:[N,14], W:[14,128]
__global__ void k_proj(const float* __restrict__ x, const float* __restrict__ W,
                       const float* __restrict__ b, float* __restrict__ h, int nN) {
  int gid = blockIdx.x * 256 + threadIdx.x;
  if (gid >= nN * 128) return;
  int n = gid >> 7, f = gid & 127;
  const float* xr = x + n * 14;
  float acc = b[f];
#pragma unroll
  for (int k = 0; k < 14; ++k) acc = fmaf(xr[k], W[k * 128 + f], acc);
  h[gid] = fmaxf(acc, 0.f);
}

// ---------------------------------------------------------------- degree count
__global__ void k_count_int(const int* __restrict__ dst, int* __restrict__ cnt, int E_) {
  int e = blockIdx.x * 256 + threadIdx.x;
  if (e < E_) atomicAdd(&cnt[dst[e]], 1);
}

// ---------------------------------------------------------------- scan (3-phase)
__global__ void k_scan1(const int* __restrict__ cnt, int* __restrict__ incl,
                        int* __restrict__ bsum, int nN) {
  __shared__ int sh[256];
  int tid = threadIdx.x;
  int i = blockIdx.x * 256 + tid;
  int v = (i < nN) ? cnt[i] : 0;
  sh[tid] = v;
  __syncthreads();
#pragma unroll
  for (int off = 1; off < 256; off <<= 1) {
    int t = (tid >= off) ? sh[tid - off] : 0;
    __syncthreads();
    sh[tid] += t;
    __syncthreads();
  }
  if (i < nN) incl[i] = sh[tid];
  if (tid == 255) bsum[blockIdx.x] = sh[255];
}

__global__ void k_scan2(int* __restrict__ bsum, int nb) {
  __shared__ int sh[256];
  int tid = threadIdx.x;
  int v = (tid < nb) ? bsum[tid] : 0;
  sh[tid] = v;
  __syncthreads();
#pragma unroll
  for (int off = 1; off < 256; off <<= 1) {
    int t = (tid >= off) ? sh[tid - off] : 0;
    __syncthreads();
    sh[tid] += t;
    __syncthreads();
  }
  if (tid < nb) bsum[tid] = sh[tid] - v;  // exclusive
}

__global__ void k_scan3(const int* __restrict__ incl, const int* __restrict__ bsum,
                        const int* __restrict__ cnt, int* __restrict__ rowptr, int nN) {
  int i = blockIdx.x * 256 + threadIdx.x;
  if (i < nN) rowptr[i] = incl[i] - cnt[i] + bsum[blockIdx.x];
}

// ---------------------------------------------------------------- CSR fill
__global__ void k_fill(const int* __restrict__ src, const int* __restrict__ dst,
                       const int* __restrict__ rowptr, int* __restrict__ cursor,
                       int* __restrict__ eSrc, int E_) {
  int e = blockIdx.x * 256 + threadIdx.x;
  if (e >= E_) return;
  int d = dst[e];
  int pos = rowptr[d] + atomicAdd(&cursor[d], 1);
  eSrc[pos] = src[e];
}

// ---------------------------------------------------------------- SAGE gather-mean
// agg[n] = mean over incoming edges of h[src]; 32 lanes/node, float4/lane
__global__ void k_sage_gather(const float4* __restrict__ h4, const int* __restrict__ rowptr,
                              const int* __restrict__ cnt, const int* __restrict__ eSrc,
                              float4* __restrict__ agg, int nN) {
  int t = blockIdx.x * 256 + threadIdx.x;
  int n = t >> 5;
  if (n >= nN) return;
  int lane = t & 31;
  int beg = rowptr[n], c = cnt[n];
  float ax = 0.f, ay = 0.f, az = 0.f, aw = 0.f;
  for (int i = 0; i < c; ++i) {
    int s = eSrc[beg + i];
    float4 v = h4[(size_t)s * 32 + lane];
    ax += v.x; ay += v.y; az += v.z; aw += v.w;
  }
  float inv = 1.f / fmaxf((float)c, 1.f);
  agg[(size_t)n * 32 + lane] = make_float4(ax * inv, ay * inv, az * inv, aw * inv);
}

// ---------------------------------------------------------------- fused SAGE layer
// Hout = relu(LN( [agg | Hin] @ [Wl;Wr] + bias )) + Hin   (agg pre-meaned)
__global__ __launch_bounds__(256)
void k_sage(const float* __restrict__ S, const float* __restrict__ Hin,
            const float* __restrict__ Wl, const float* __restrict__ Wr,
            const float* __restrict__ bias, const float* __restrict__ gam,
            const float* __restrict__ bet, float* __restrict__ Hout, int nN) {
  __shared__ float As[32][65];
  __shared__ float Bs[32][128];
  int tid = threadIdx.x;
  int tx = tid & 31, ty = tid >> 5;
  int rowBase = blockIdx.x * 64;
  float acc[8][4];
#pragma unroll
  for (int i = 0; i < 8; ++i)
#pragma unroll
    for (int j = 0; j < 4; ++j) acc[i][j] = 0.f;

  int lm = tid >> 2;           // 0..63  (tile row)
  int lk = (tid & 3) * 8;      // 0,8,16,24
  int bkr = tid >> 3;          // 0..31
  int bcq = (tid & 7) * 16;    // 0..112

  for (int k0 = 0; k0 < 256; k0 += 32) {
    int grow = rowBase + lm;
    if (grow < nN) {
      const float* p = (k0 < 128) ? (S + (size_t)grow * 128 + k0 + lk)
                                  : (Hin + (size_t)grow * 128 + (k0 - 128) + lk);
#pragma unroll
      for (int u = 0; u < 8; ++u) As[lk + u][lm] = p[u];
    } else {
#pragma unroll
      for (int u = 0; u < 8; ++u) As[lk + u][lm] = 0.f;
    }
    {
      int gk = k0 + bkr;
      const float* bp = (gk < 128) ? (Wl + (size_t)gk * 128 + bcq)
                                   : (Wr + (size_t)(gk - 128) * 128 + bcq);
#pragma unroll
      for (int u = 0; u < 4; ++u) {
        float4 v = *(const float4*)(bp + 4 * u);
        *(float4*)&Bs[bkr][bcq + 4 * u] = v;
      }
    }
    __syncthreads();
#pragma unroll
    for (int kk = 0; kk < 32; ++kk) {
      float b0 = Bs[kk][tx], b1 = Bs[kk][tx + 32], b2 = Bs[kk][tx + 64], b3 = Bs[kk][tx + 96];
#pragma unroll
      for (int i = 0; i < 8; ++i) {
        float a = As[kk][ty + 8 * i];
        acc[i][0] = fmaf(a, b0, acc[i][0]);
        acc[i][1] = fmaf(a, b1, acc[i][1]);
        acc[i][2] = fmaf(a, b2, acc[i][2]);
        acc[i][3] = fmaf(a, b3, acc[i][3]);
      }
    }
    __syncthreads();
  }

  float bi0 = bias[tx], bi1 = bias[tx + 32], bi2 = bias[tx + 64], bi3 = bias[tx + 96];
  float g0 = gam[tx], g1 = gam[tx + 32], g2 = gam[tx + 64], g3v = gam[tx + 96];
  float e0 = bet[tx], e1 = bet[tx + 32], e2 = bet[tx + 64], e3 = bet[tx + 96];
#pragma unroll
  for (int i = 0; i < 8; ++i) {
    int grow = rowBase + ty + 8 * i;
    float v0 = acc[i][0] + bi0, v1 = acc[i][1] + bi1, v2 = acc[i][2] + bi2, v3 = acc[i][3] + bi3;
    float s1 = v0 + v1 + v2 + v3;
    float s2 = v0 * v0 + v1 * v1 + v2 * v2 + v3 * v3;
#pragma unroll
    for (int m = 16; m >= 1; m >>= 1) { s1 += __shfl_xor(s1, m); s2 += __shfl_xor(s2, m); }
    float mean = s1 * (1.f / 128.f);
    float var = s2 * (1.f / 128.f) - mean * mean;
    float rstd = rsqrtf(var + EPSV);
    if (grow < nN) {
      const float* res = Hin + (size_t)grow * 128;
      float* o = Hout + (size_t)grow * 128;
      o[tx]      = fmaxf((v0 - mean) * rstd * g0 + e0, 0.f) + res[tx];
      o[tx + 32] = fmaxf((v1 - mean) * rstd * g1 + e1, 0.f) + res[tx + 32];
      o[tx + 64] = fmaxf((v2 - mean) * rstd * g2 + e2, 0.f) + res[tx + 64];
      o[tx + 96] = fmaxf((v3 - mean) * rstd * g3v + e3, 0.f) + res[tx + 96];
    }
  }
}

// ---------------------------------------------------------------- GAT GEMM + att logits
// G[N,256] = A[N,128] @ Wg[128,256]; also as_[n,h], ad_[n,h] from registers
__global__ __launch_bounds__(256)
void k_gemm_gat(const float* __restrict__ A, const float* __restrict__ Wg,
                const float* __restrict__ atts, const float* __restrict__ attd,
                float* __restrict__ G, float* __restrict__ as_, float* __restrict__ ad_,
                int nN) {
  __shared__ float As[32][65];
  __shared__ float Bs[32][256];
  int tid = threadIdx.x;
  int tx = tid & 31, ty = tid >> 5;
  int rowBase = blockIdx.x * 64;
  float acc[8][8];
#pragma unroll
  for (int i = 0; i < 8; ++i)
#pragma unroll
    for (int j = 0; j < 8; ++j) acc[i][j] = 0.f;

  int lm = tid >> 2, lk = (tid & 3) * 8;
  int bkr = tid >> 3, bcq = (tid & 7) * 32;

  for (int k0 = 0; k0 < 128; k0 += 32) {
    int grow = rowBase + lm;
    if (grow < nN) {
      const float* p = A + (size_t)grow * 128 + k0 + lk;
#pragma unroll
      for (int u = 0; u < 8; ++u) As[lk + u][lm] = p[u];
    } else {
#pragma unroll
      for (int u = 0; u < 8; ++u) As[lk + u][lm] = 0.f;
    }
    {
      const float* bp = Wg + (size_t)(k0 + bkr) * 256 + bcq;
#pragma unroll
      for (int u = 0; u < 8; ++u) {
        float4 v = *(const float4*)(bp + 4 * u);
        *(float4*)&Bs[bkr][bcq + 4 * u] = v;
      }
    }
    __syncthreads();
#pragma unroll
    for (int kk = 0; kk < 32; ++kk) {
      float br[8];
#pragma unroll
      for (int j = 0; j < 8; ++j) br[j] = Bs[kk][tx + 32 * j];
#pragma unroll
      for (int i = 0; i < 8; ++i) {
        float a = As[kk][ty + 8 * i];
#pragma unroll
        for (int j = 0; j < 8; ++j) acc[i][j] = fmaf(a, br[j], acc[i][j]);
      }
    }
    __syncthreads();
  }

  float atts_r[8], attd_r[8];
#pragma unroll
  for (int j = 0; j < 8; ++j) { atts_r[j] = atts[tx + 32 * j]; attd_r[j] = attd[tx + 32 * j]; }

#pragma unroll
  for (int i = 0; i < 8; ++i) {
    int grow = rowBase + ty + 8 * i;
    if (grow < nN) {
      float* o = G + (size_t)grow * 256;
#pragma unroll
      for (int j = 0; j < 8; ++j) o[tx + 32 * j] = acc[i][j];
    }
    // att logits: head h covers cols j=2h, 2h+1
    float p_s[4], p_d[4];
#pragma unroll
    for (int h = 0; h < 4; ++h) {
      p_s[h] = acc[i][2 * h] * atts_r[2 * h] + acc[i][2 * h + 1] * atts_r[2 * h + 1];
      p_d[h] = acc[i][2 * h] * attd_r[2 * h] + acc[i][2 * h + 1] * attd_r[2 * h + 1];
    }
#pragma unroll
    for (int m = 16; m >= 1; m >>= 1) {
#pragma unroll
      for (int h = 0; h < 4; ++h) { p_s[h] += __shfl_xor(p_s[h], m); p_d[h] += __shfl_xor(p_d[h], m); }
    }
    if (tx == 0 && grow < nN) {
#pragma unroll
      for (int h = 0; h < 4; ++h) { as_[grow * 4 + h] = p_s[h]; ad_[grow * 4 + h] = p_d[h]; }
    }
  }
}

// ---------------------------------------------------------------- fused GAT gather + finalize + LN
// 64 lanes/node. acc = self + sum_e w_e * G[src_e]; out = LN(mean_h(acc_h/den_h) + bg)
__global__ void k_gat(const float4* __restrict__ G4, const int* __restrict__ rowptr,
                      const int* __restrict__ cnt, const int* __restrict__ eSrc,
                      const float* __restrict__ as_, const float* __restrict__ ad_,
                      const float* __restrict__ bg, const float* __restrict__ g3,
                      const float* __restrict__ be3, float* __restrict__ out, int nN) {
  int t = blockIdx.x * 256 + threadIdx.x;
  int n = t >> 6;
  if (n >= nN) return;
  int lane = t & 63;
  int h = lane >> 4;
  float adn = ad_[n * 4 + h];

  // self loop
  float e0 = as_[n * 4 + h] + adn;
  e0 = e0 > 0.f ? e0 : 0.2f * e0;
  float w = expf(e0);
  float4 g = G4[(size_t)n * 64 + lane];
  float ax = w * g.x, ay = w * g.y, az = w * g.z, aw = w * g.w;
  float den = w;

  int beg = rowptr[n], c = cnt[n];
  for (int i = 0; i < c; ++i) {
    int s = eSrc[beg + i];
    float ev = as_[s * 4 + h] + adn;
    ev = ev > 0.f ? ev : 0.2f * ev;
    w = expf(ev);
    float4 v = G4[(size_t)s * 64 + lane];
    ax = fmaf(w, v.x, ax); ay = fmaf(w, v.y, ay);
    az = fmaf(w, v.z, az); aw = fmaf(w, v.w, aw);
    den += w;
  }
  float inv = 1.f / den;
  ax *= inv; ay *= inv; az *= inv; aw *= inv;

  // head-mean: sum over lane bits 4,5 (the head index)
#pragma unroll
  for (int m = 32; m >= 16; m >>= 1) {
    ax += __shfl_xor(ax, m); ay += __shfl_xor(ay, m);
    az += __shfl_xor(az, m); aw += __shfl_xor(aw, m);
  }
  int fb = (lane & 15) * 4;
  float v0 = ax * 0.25f + bg[fb];
  float v1 = ay * 0.25f + bg[fb + 1];
  float v2 = az * 0.25f + bg[fb + 2];
  float v3 = aw * 0.25f + bg[fb + 3];

  // LN over 64 features (each 16-lane subgroup holds all 64)
  float s1 = v0 + v1 + v2 + v3;
  float s2 = v0 * v0 + v1 * v1 + v2 * v2 + v3 * v3;
#pragma unroll
  for (int m = 8; m >= 1; m >>= 1) { s1 += __shfl_xor(s1, m); s2 += __shfl_xor(s2, m); }
  float mean = s1 * (1.f / 64.f);
  float var = s2 * (1.f / 64.f) - mean * mean;
  float rstd = rsqrtf(var + EPSV);
  if ((lane >> 4) == 0) {
    float4 o;
    o.x = (v0 - mean) * rstd * g3[fb] + be3[fb];
    o.y = (v1 - mean) * rstd * g3[fb + 1] + be3[fb + 1];
    o.z = (v2 - mean) * rstd * g3[fb + 2] + be3[fb + 2];
    o.w = (v3 - mean) * rstd * g3[fb + 3] + be3[fb + 3];
    *(float4*)(out + (size_t)n * 64 + fb) = o;
  }
}

// ================================================================ launch
extern "C" void kernel_launch(void* const* d_in, const int* in_sizes, int n_in,
                              void* d_out, int out_size, void* d_ws, size_t ws_size,
                              hipStream_t stream) {
  const float* x    = (const float*)d_in[0];
  const int*   edge = (const int*)d_in[1];
  const float* W_in = (const float*)d_in[2];
  const float* b_in = (const float*)d_in[3];
  const float* W1_l = (const float*)d_in[4];
  const float* b1   = (const float*)d_in[5];
  const float* W1_r = (const float*)d_in[6];
  const float* g1   = (const float*)d_in[7];
  const float* be1  = (const float*)d_in[8];
  const float* W2_l = (const float*)d_in[9];
  const float* b2   = (const float*)d_in[10];
  const float* W2_r = (const float*)d_in[11];
  const float* g2   = (const float*)d_in[12];
  const float* be2  = (const float*)d_in[13];
  const float* W_g  = (const float*)d_in[14];
  const float* atts = (const float*)d_in[15];
  const float* attd = (const float*)d_in[16];
  const float* b_g  = (const float*)d_in[17];
  const float* g3   = (const float*)d_in[18];
  const float* be3  = (const float*)d_in[19];

  const int nN = in_sizes[0] / 14;
  const int E_ = in_sizes[1] / 2;
  const int* src = edge;
  const int* dst = edge + E_;

  float* WS  = (float*)d_ws;
  float* Ab  = WS;                           // N*128
  float* Sb  = WS + (size_t)nN * 128;        // N*128
  float* Bb  = WS + (size_t)nN * 256;        // N*128
  float* Gb  = WS + (size_t)nN * 128;        // N*256 (aliases Sb+Bb; used only after both dead)
  float* AS_ = WS + (size_t)nN * 384;        // N*4
  float* AD_ = AS_ + (size_t)nN * 4;         // N*4
  int*   I      = (int*)(AD_ + (size_t)nN * 4);
  int*   cntI   = I;                         // N
  int*   rowptr = I + nN;                    // N
  int*   cursor = I + 2 * (size_t)nN;        // N
  int*   incl   = I + 3 * (size_t)nN;        // N
  int*   bsum   = I + 4 * (size_t)nN;        // 1024
  int*   eSrc   = bsum + 1024;               // E

  const int SB = (nN + 255) / 256;  // scan blocks (196 for N=50000, must be <=256)

  hipMemsetAsync(cntI, 0, (size_t)nN * sizeof(int), stream);
  hipMemsetAsync(cursor, 0, (size_t)nN * sizeof(int), stream);

  // CSR by dst
  k_count_int<<<(E_ + 255) / 256, 256, 0, stream>>>(dst, cntI, E_);
  k_scan1<<<SB, 256, 0, stream>>>(cntI, incl, bsum, nN);
  k_scan2<<<1, 256, 0, stream>>>(bsum, SB);
  k_scan3<<<SB, 256, 0, stream>>>(incl, bsum, cntI, rowptr, nN);
  k_fill<<<(E_ + 255) / 256, 256, 0, stream>>>(src, dst, rowptr, cursor, eSrc, E_);

  // input projection -> Ab (h0)
  k_proj<<<(nN * 128 + 255) / 256, 256, 0, stream>>>(x, W_in, b_in, Ab, nN);

  // SAGE layer 1: Ab -> Bb
  k_sage_gather<<<(nN * 32 + 255) / 256, 256, 0, stream>>>((const float4*)Ab, rowptr, cntI, eSrc, (float4*)Sb, nN);
  k_sage<<<(nN + 63) / 64, 256, 0, stream>>>(Sb, Ab, W1_l, W1_r, b1, g1, be1, Bb, nN);

  // SAGE layer 2: Bb -> Ab
  k_sage_gather<<<(nN * 32 + 255) / 256, 256, 0, stream>>>((const float4*)Bb, rowptr, cntI, eSrc, (float4*)Sb, nN);
  k_sage<<<(nN + 63) / 64, 256, 0, stream>>>(Sb, Bb, W2_l, W2_r, b2, g2, be2, Ab, nN);

  // GAT: Ab -> Gb (+logits) -> out   (Sb, Bb dead; Gb aliases them)
  k_gemm_gat<<<(nN + 63) / 64, 256, 0, stream>>>(Ab, W_g, atts, attd, Gb, AS_, AD_, nN);
  k_gat<<<(nN * 64 + 255) / 256, 256, 0, stream>>>((const float4*)Gb, rowptr, cntI, eSrc, AS_, AD_, b_g, g3, be3, (float*)d_out, nN);
}

// Round 4
// 346.115 us; speedup vs baseline: 12.7568x; 1.6307x over previous
//
#include <hip/hip_runtime.h>
#include <math.h>

#define EPSV 1e-5f

typedef __attribute__((ext_vector_type(8))) short short8;
typedef __attribute__((ext_vector_type(4))) float f32x4;

__device__ __forceinline__ unsigned short f2b(float f) {
  union { float f; unsigned int u; } c; c.f = f;
  unsigned int u = c.u + 0x7fffu + ((c.u >> 16) & 1u);
  return (unsigned short)(u >> 16);
}
__device__ __forceinline__ float b2f(unsigned short h) {
  union { unsigned int u; float f; } c; c.u = ((unsigned int)h) << 16;
  return c.f;
}

// ---------------------------------------------------------------- weight prep
// WlT[n][k]=bf16(Wl[k][n]) (128x128), WrT same, WgT[n][k]=bf16(Wg[k][n]) (256x128)
__global__ void k_prep(const float* __restrict__ Wl, const float* __restrict__ Wr,
                       const float* __restrict__ Wg, unsigned short* __restrict__ WlT,
                       unsigned short* __restrict__ WrT, unsigned short* __restrict__ WgT) {
  int id = blockIdx.x * 256 + threadIdx.x;  // 0..65535
  if (id < 16384) {
    int n = id >> 7, k = id & 127;
    WlT[id] = f2b(Wl[k * 128 + n]);
  } else if (id < 32768) {
    int j = id - 16384; int n = j >> 7, k = j & 127;
    WrT[j] = f2b(Wr[k * 128 + n]);
  } else {
    int j = id - 32768; int n = j >> 7, k = j & 127;
    WgT[j] = f2b(Wg[k * 256 + n]);
  }
}

// ---------------------------------------------------------------- input proj
__global__ void k_proj(const float* __restrict__ x, const float* __restrict__ W,
                       const float* __restrict__ b, float* __restrict__ h,
                       unsigned short* __restrict__ h16, int nN) {
  int gid = blockIdx.x * 256 + threadIdx.x;
  if (gid >= nN * 128) return;
  int n = gid >> 7, f = gid & 127;
  const float* xr = x + n * 14;
  float acc = b[f];
#pragma unroll
  for (int k = 0; k < 14; ++k) acc = fmaf(xr[k], W[k * 128 + f], acc);
  float o = fmaxf(acc, 0.f);
  h[gid] = o;
  h16[gid] = f2b(o);
}

// ---------------------------------------------------------------- degree count
__global__ void k_count_int(const int* __restrict__ dst, int* __restrict__ cnt, int E_) {
  int e = blockIdx.x * 256 + threadIdx.x;
  if (e < E_) atomicAdd(&cnt[dst[e]], 1);
}

// ---------------------------------------------------------------- scan (3-phase)
__global__ void k_scan1(const int* __restrict__ cnt, int* __restrict__ incl,
                        int* __restrict__ bsum, int nN) {
  __shared__ int sh[256];
  int tid = threadIdx.x;
  int i = blockIdx.x * 256 + tid;
  int v = (i < nN) ? cnt[i] : 0;
  sh[tid] = v;
  __syncthreads();
#pragma unroll
  for (int off = 1; off < 256; off <<= 1) {
    int t = (tid >= off) ? sh[tid - off] : 0;
    __syncthreads();
    sh[tid] += t;
    __syncthreads();
  }
  if (i < nN) incl[i] = sh[tid];
  if (tid == 255) bsum[blockIdx.x] = sh[255];
}

__global__ void k_scan2(int* __restrict__ bsum, int nb) {
  __shared__ int sh[256];
  int tid = threadIdx.x;
  int v = (tid < nb) ? bsum[tid] : 0;
  sh[tid] = v;
  __syncthreads();
#pragma unroll
  for (int off = 1; off < 256; off <<= 1) {
    int t = (tid >= off) ? sh[tid - off] : 0;
    __syncthreads();
    sh[tid] += t;
    __syncthreads();
  }
  if (tid < nb) bsum[tid] = sh[tid] - v;  // exclusive
}

__global__ void k_scan3(const int* __restrict__ incl, const int* __restrict__ bsum,
                        const int* __restrict__ cnt, int* __restrict__ rowptr, int nN) {
  int i = blockIdx.x * 256 + threadIdx.x;
  if (i < nN) rowptr[i] = incl[i] - cnt[i] + bsum[blockIdx.x];
}

// ---------------------------------------------------------------- CSR fill
__global__ void k_fill(const int* __restrict__ src, const int* __restrict__ dst,
                       const int* __restrict__ rowptr, int* __restrict__ cursor,
                       int* __restrict__ eSrc, int E_) {
  int e = blockIdx.x * 256 + threadIdx.x;
  if (e >= E_) return;
  int d = dst[e];
  int pos = rowptr[d] + atomicAdd(&cursor[d], 1);
  eSrc[pos] = src[e];
}

// ---------------------------------------------------------------- SAGE gather-mean (bf16)
// 32 lanes/node, 4 feats/lane (ushort4 = 8B)
__global__ void k_sage_gather16(const unsigned short* __restrict__ h16,
                                const int* __restrict__ rowptr, const int* __restrict__ cnt,
                                const int* __restrict__ eSrc,
                                unsigned short* __restrict__ agg16, int nN) {
  int t = blockIdx.x * 256 + threadIdx.x;
  int n = t >> 5;
  if (n >= nN) return;
  int lane = t & 31;
  int beg = rowptr[n], c = cnt[n];
  float ax = 0.f, ay = 0.f, az = 0.f, aw = 0.f;
  for (int i = 0; i < c; ++i) {
    int s = eSrc[beg + i];
    ushort4 q = *(const ushort4*)(h16 + (size_t)s * 128 + lane * 4);
    ax += b2f(q.x); ay += b2f(q.y); az += b2f(q.z); aw += b2f(q.w);
  }
  float inv = 1.f / fmaxf((float)c, 1.f);
  unsigned short* o = agg16 + (size_t)n * 128 + lane * 4;
  ushort4 r;
  r.x = f2b(ax * inv); r.y = f2b(ay * inv); r.z = f2b(az * inv); r.w = f2b(aw * inv);
  *(ushort4*)o = r;
}

// ---------------------------------------------------------------- SAGE MFMA layer
// Hout = relu(LN([agg|Hin] @ [Wl;Wr] + bias)) + Hin ; 64 rows/block, 4 waves
__global__ __launch_bounds__(256)
void k_sage_mfma(const unsigned short* __restrict__ agg16,
                 const unsigned short* __restrict__ hin16,
                 const float* __restrict__ hinf,
                 const unsigned short* __restrict__ WlT,
                 const unsigned short* __restrict__ WrT,
                 const float* __restrict__ bias, const float* __restrict__ gam,
                 const float* __restrict__ bet, float* __restrict__ houtf,
                 unsigned short* __restrict__ hout16, int nN) {
  __shared__ unsigned short lA[64][136];
  __shared__ unsigned short lB[128][136];
  int tid = threadIdx.x;
  int wave = tid >> 6, lane = tid & 63;
  int cl = lane & 15, g = lane >> 4;
  int rowBase = blockIdx.x * 64;
  f32x4 acc[8];
#pragma unroll
  for (int ct = 0; ct < 8; ++ct) acc[ct] = (f32x4){0.f, 0.f, 0.f, 0.f};

  int ar = tid >> 2, ap = (tid & 3) * 32;  // A stage: row, k-part
  int br = tid >> 1, bp = (tid & 1) * 64;  // B stage: row, k-part

  for (int half = 0; half < 2; ++half) {
    const unsigned short* At = half ? hin16 : agg16;
    const unsigned short* Bt = half ? WrT : WlT;
    if (half) __syncthreads();
    {
      int grow = rowBase + ar;
      if (grow < nN) {
        const unsigned short* sp = At + (size_t)grow * 128 + ap;
#pragma unroll
        for (int u = 0; u < 4; ++u)
          *(short8*)&lA[ar][ap + u * 8] = *(const short8*)(sp + u * 8);
      } else {
        short8 z = {0, 0, 0, 0, 0, 0, 0, 0};
#pragma unroll
        for (int u = 0; u < 4; ++u) *(short8*)&lA[ar][ap + u * 8] = z;
      }
      const unsigned short* bsp = Bt + (size_t)br * 128 + bp;
#pragma unroll
      for (int u = 0; u < 8; ++u)
        *(short8*)&lB[br][bp + u * 8] = *(const short8*)(bsp + u * 8);
    }
    __syncthreads();
#pragma unroll
    for (int ks = 0; ks < 4; ++ks) {
      short8 a = *(const short8*)&lA[wave * 16 + cl][ks * 32 + g * 8];
#pragma unroll
      for (int ct = 0; ct < 8; ++ct) {
        short8 b = *(const short8*)&lB[ct * 16 + cl][ks * 32 + g * 8];
        acc[ct] = __builtin_amdgcn_mfma_f32_16x16x32_bf16(a, b, acc[ct], 0, 0, 0);
      }
    }
  }
  __syncthreads();

  // epilogue: +bias, LN over 128 cols, *gam+bet, relu, +residual
  float bcol[8], gcol[8], ecol[8];
#pragma unroll
  for (int ct = 0; ct < 8; ++ct) {
    int c = ct * 16 + cl;
    bcol[ct] = bias[c]; gcol[ct] = gam[c]; ecol[ct] = bet[c];
  }
  float v[8][4];
  float s1[4] = {0.f, 0.f, 0.f, 0.f}, s2[4] = {0.f, 0.f, 0.f, 0.f};
#pragma unroll
  for (int ct = 0; ct < 8; ++ct)
#pragma unroll
    for (int r = 0; r < 4; ++r) {
      float t = acc[ct][r] + bcol[ct];
      v[ct][r] = t;
      s1[r] += t; s2[r] += t * t;
    }
#pragma unroll
  for (int m = 1; m <= 8; m <<= 1)
#pragma unroll
    for (int r = 0; r < 4; ++r) { s1[r] += __shfl_xor(s1[r], m); s2[r] += __shfl_xor(s2[r], m); }

#pragma unroll
  for (int r = 0; r < 4; ++r) {
    float mean = s1[r] * (1.f / 128.f);
    float var = s2[r] * (1.f / 128.f) - mean * mean;
    float rstd = rsqrtf(var + EPSV);
    int grow = rowBase + wave * 16 + g * 4 + r;
    if (grow < nN) {
#pragma unroll
      for (int ct = 0; ct < 8; ++ct) {
        int c = ct * 16 + cl;
        float o = fmaxf((v[ct][r] - mean) * rstd * gcol[ct] + ecol[ct], 0.f)
                  + hinf[(size_t)grow * 128 + c];
        houtf[(size_t)grow * 128 + c] = o;
        hout16[(size_t)grow * 128 + c] = f2b(o);
      }
    }
  }
}

// ---------------------------------------------------------------- GAT GEMM (MFMA) + logits
// G[:,y*128..y*128+127] = h @ Wg[:, half y]; logits for heads 2y, 2y+1
__global__ __launch_bounds__(256)
void k_gatgemm(const unsigned short* __restrict__ h16, const unsigned short* __restrict__ WgT,
               const float* __restrict__ atts, const float* __restrict__ attd,
               unsigned short* __restrict__ G16, float* __restrict__ as_,
               float* __restrict__ ad_, int nN) {
  __shared__ unsigned short lA[64][136];
  __shared__ unsigned short lB[128][136];
  int tid = threadIdx.x;
  int wave = tid >> 6, lane = tid & 63;
  int cl = lane & 15, g = lane >> 4;
  int rowBase = blockIdx.x * 64;
  int y = blockIdx.y;
  f32x4 acc[8];
#pragma unroll
  for (int ct = 0; ct < 8; ++ct) acc[ct] = (f32x4){0.f, 0.f, 0.f, 0.f};

  int ar = tid >> 2, ap = (tid & 3) * 32;
  int br = tid >> 1, bp = (tid & 1) * 64;
  {
    int grow = rowBase + ar;
    if (grow < nN) {
      const unsigned short* sp = h16 + (size_t)grow * 128 + ap;
#pragma unroll
      for (int u = 0; u < 4; ++u)
        *(short8*)&lA[ar][ap + u * 8] = *(const short8*)(sp + u * 8);
    } else {
      short8 z = {0, 0, 0, 0, 0, 0, 0, 0};
#pragma unroll
      for (int u = 0; u < 4; ++u) *(short8*)&lA[ar][ap + u * 8] = z;
    }
    const unsigned short* bsp = WgT + (size_t)(y * 128 + br) * 128 + bp;
#pragma unroll
    for (int u = 0; u < 8; ++u)
      *(short8*)&lB[br][bp + u * 8] = *(const short8*)(bsp + u * 8);
  }
  __syncthreads();
#pragma unroll
  for (int ks = 0; ks < 4; ++ks) {
    short8 a = *(const short8*)&lA[wave * 16 + cl][ks * 32 + g * 8];
#pragma unroll
    for (int ct = 0; ct < 8; ++ct) {
      short8 b = *(const short8*)&lB[ct * 16 + cl][ks * 32 + g * 8];
      acc[ct] = __builtin_amdgcn_mfma_f32_16x16x32_bf16(a, b, acc[ct], 0, 0, 0);
    }
  }

  // epilogue: store G16 + attention logits for heads 2y+hh (hh = ct>>2)
  float atr[8], adr[8];
#pragma unroll
  for (int ct = 0; ct < 8; ++ct) {
    int h = y * 2 + (ct >> 2);
    int w = (ct & 3) * 16 + cl;  // col within head
    atr[ct] = atts[h * 64 + w];
    adr[ct] = attd[h * 64 + w];
  }
  float ps[2][4], pd[2][4];
#pragma unroll
  for (int hh = 0; hh < 2; ++hh)
#pragma unroll
    for (int r = 0; r < 4; ++r) { ps[hh][r] = 0.f; pd[hh][r] = 0.f; }

#pragma unroll
  for (int r = 0; r < 4; ++r) {
    int grow = rowBase + wave * 16 + g * 4 + r;
    if (grow < nN) {
      unsigned short* op = G16 + (size_t)grow * 256 + y * 128 + cl;
#pragma unroll
      for (int ct = 0; ct < 8; ++ct) op[ct * 16] = f2b(acc[ct][r]);
    }
#pragma unroll
    for (int ct = 0; ct < 8; ++ct) {
      ps[ct >> 2][r] = fmaf(acc[ct][r], atr[ct], ps[ct >> 2][r]);
      pd[ct >> 2][r] = fmaf(acc[ct][r], adr[ct], pd[ct >> 2][r]);
    }
  }
#pragma unroll
  for (int m = 1; m <= 8; m <<= 1)
#pragma unroll
    for (int hh = 0; hh < 2; ++hh)
#pragma unroll
      for (int r = 0; r < 4; ++r) {
        ps[hh][r] += __shfl_xor(ps[hh][r], m);
        pd[hh][r] += __shfl_xor(pd[hh][r], m);
      }
  if (cl == 0) {
#pragma unroll
    for (int r = 0; r < 4; ++r) {
      int grow = rowBase + wave * 16 + g * 4 + r;
      if (grow < nN) {
#pragma unroll
        for (int hh = 0; hh < 2; ++hh) {
          as_[grow * 4 + y * 2 + hh] = ps[hh][r];
          ad_[grow * 4 + y * 2 + hh] = pd[hh][r];
        }
      }
    }
  }
}

// ---------------------------------------------------------------- fused GAT gather + LN (bf16 G)
__global__ void k_gat(const unsigned short* __restrict__ G16, const int* __restrict__ rowptr,
                      const int* __restrict__ cnt, const int* __restrict__ eSrc,
                      const float* __restrict__ as_, const float* __restrict__ ad_,
                      const float* __restrict__ bg, const float* __restrict__ g3,
                      const float* __restrict__ be3, float* __restrict__ out, int nN) {
  int t = blockIdx.x * 256 + threadIdx.x;
  int n = t >> 6;
  if (n >= nN) return;
  int lane = t & 63;
  int h = lane >> 4;
  float adn = ad_[n * 4 + h];

  // self loop
  float e0 = as_[n * 4 + h] + adn;
  e0 = e0 > 0.f ? e0 : 0.2f * e0;
  float w = expf(e0);
  ushort4 q = *(const ushort4*)(G16 + (size_t)n * 256 + lane * 4);
  float ax = w * b2f(q.x), ay = w * b2f(q.y), az = w * b2f(q.z), aw = w * b2f(q.w);
  float den = w;

  int beg = rowptr[n], c = cnt[n];
  for (int i = 0; i < c; ++i) {
    int s = eSrc[beg + i];
    float ev = as_[s * 4 + h] + adn;
    ev = ev > 0.f ? ev : 0.2f * ev;
    w = expf(ev);
    q = *(const ushort4*)(G16 + (size_t)s * 256 + lane * 4);
    ax = fmaf(w, b2f(q.x), ax); ay = fmaf(w, b2f(q.y), ay);
    az = fmaf(w, b2f(q.z), az); aw = fmaf(w, b2f(q.w), aw);
    den += w;
  }
  float inv = 1.f / den;
  ax *= inv; ay *= inv; az *= inv; aw *= inv;

  // head-mean over lane bits 4,5
#pragma unroll
  for (int m = 32; m >= 16; m >>= 1) {
    ax += __shfl_xor(ax, m); ay += __shfl_xor(ay, m);
    az += __shfl_xor(az, m); aw += __shfl_xor(aw, m);
  }
  int fb = (lane & 15) * 4;
  float v0 = ax * 0.25f + bg[fb];
  float v1 = ay * 0.25f + bg[fb + 1];
  float v2 = az * 0.25f + bg[fb + 2];
  float v3 = aw * 0.25f + bg[fb + 3];

  float s1 = v0 + v1 + v2 + v3;
  float s2 = v0 * v0 + v1 * v1 + v2 * v2 + v3 * v3;
#pragma unroll
  for (int m = 8; m >= 1; m >>= 1) { s1 += __shfl_xor(s1, m); s2 += __shfl_xor(s2, m); }
  float mean = s1 * (1.f / 64.f);
  float var = s2 * (1.f / 64.f) - mean * mean;
  float rstd = rsqrtf(var + EPSV);
  if ((lane >> 4) == 0) {
    float4 o;
    o.x = (v0 - mean) * rstd * g3[fb] + be3[fb];
    o.y = (v1 - mean) * rstd * g3[fb + 1] + be3[fb + 1];
    o.z = (v2 - mean) * rstd * g3[fb + 2] + be3[fb + 2];
    o.w = (v3 - mean) * rstd * g3[fb + 3] + be3[fb + 3];
    *(float4*)(out + (size_t)n * 64 + fb) = o;
  }
}

// ================================================================ launch
extern "C" void kernel_launch(void* const* d_in, const int* in_sizes, int n_in,
                              void* d_out, int out_size, void* d_ws, size_t ws_size,
                              hipStream_t stream) {
  const float* x    = (const float*)d_in[0];
  const int*   edge = (const int*)d_in[1];
  const float* W_in = (const float*)d_in[2];
  const float* b_in = (const float*)d_in[3];
  const float* W1_l = (const float*)d_in[4];
  const float* b1   = (const float*)d_in[5];
  const float* W1_r = (const float*)d_in[6];
  const float* g1   = (const float*)d_in[7];
  const float* be1  = (const float*)d_in[8];
  const float* W2_l = (const float*)d_in[9];
  const float* b2   = (const float*)d_in[10];
  const float* W2_r = (const float*)d_in[11];
  const float* g2   = (const float*)d_in[12];
  const float* be2  = (const float*)d_in[13];
  const float* W_g  = (const float*)d_in[14];
  const float* atts = (const float*)d_in[15];
  const float* attd = (const float*)d_in[16];
  const float* b_g  = (const float*)d_in[17];
  const float* g3   = (const float*)d_in[18];
  const float* be3  = (const float*)d_in[19];

  const int nN = in_sizes[0] / 14;
  const int E_ = in_sizes[1] / 2;
  const int* src = edge;
  const int* dst = edge + E_;

  char* W = (char*)d_ws;
  float* hA = (float*)W;                 W += (size_t)nN * 128 * 4;
  float* hB = (float*)W;                 W += (size_t)nN * 128 * 4;
  unsigned short* hA16  = (unsigned short*)W; W += (size_t)nN * 128 * 2;
  unsigned short* hB16  = (unsigned short*)W; W += (size_t)nN * 128 * 2;
  unsigned short* agg16 = (unsigned short*)W; W += (size_t)nN * 128 * 2;
  unsigned short* G16   = (unsigned short*)W; W += (size_t)nN * 256 * 2;
  unsigned short* WlT   = (unsigned short*)W; W += 16384 * 2;
  unsigned short* WrT   = (unsigned short*)W; W += 16384 * 2;
  unsigned short* WgT   = (unsigned short*)W; W += 32768 * 2;
  float* AS_ = (float*)W;                W += (size_t)nN * 4 * 4;
  float* AD_ = (float*)W;                W += (size_t)nN * 4 * 4;
  int* cntI   = (int*)W;                 W += (size_t)nN * 4;
  int* rowptr = (int*)W;                 W += (size_t)nN * 4;
  int* cursor = (int*)W;                 W += (size_t)nN * 4;
  int* incl   = (int*)W;                 W += (size_t)nN * 4;
  int* bsum   = (int*)W;                 W += 1024 * 4;
  int* eSrc   = (int*)W;

  const int SB = (nN + 255) / 256;  // 196 for N=50000 (must be <=256)
  const int NB = (nN + 63) / 64;

  hipMemsetAsync(cntI, 0, (size_t)nN * sizeof(int), stream);
  hipMemsetAsync(cursor, 0, (size_t)nN * sizeof(int), stream);

  // CSR by dst
  k_count_int<<<(E_ + 255) / 256, 256, 0, stream>>>(dst, cntI, E_);
  k_scan1<<<SB, 256, 0, stream>>>(cntI, incl, bsum, nN);
  k_scan2<<<1, 256, 0, stream>>>(bsum, SB);
  k_scan3<<<SB, 256, 0, stream>>>(incl, bsum, cntI, rowptr, nN);
  k_fill<<<(E_ + 255) / 256, 256, 0, stream>>>(src, dst, rowptr, cursor, eSrc, E_);

  // weight prep + input projection
  k_prep<<<256, 256, 0, stream>>>(W1_l, W1_r, W_g, WlT, WrT, WgT);
  k_proj<<<(nN * 128 + 255) / 256, 256, 0, stream>>>(x, W_in, b_in, hA, hA16, nN);

  // SAGE layer 1: hA -> hB
  k_sage_gather16<<<(nN * 32 + 255) / 256, 256, 0, stream>>>(hA16, rowptr, cntI, eSrc, agg16, nN);
  k_sage_mfma<<<NB, 256, 0, stream>>>(agg16, hA16, hA, WlT, WrT, b1, g1, be1, hB, hB16, nN);

  // SAGE layer 2: hB -> hA   (re-prep: WlT/WrT now layer-2 weights)
  k_prep<<<256, 256, 0, stream>>>(W2_l, W2_r, W_g, WlT, WrT, WgT);
  k_sage_gather16<<<(nN * 32 + 255) / 256, 256, 0, stream>>>(hB16, rowptr, cntI, eSrc, agg16, nN);
  k_sage_mfma<<<NB, 256, 0, stream>>>(agg16, hB16, hB, WlT, WrT, b2, g2, be2, hA, hA16, nN);

  // GAT: hA -> G16 (+logits) -> out
  k_gatgemm<<<dim3(NB, 2), 256, 0, stream>>>(hA16, WgT, atts, attd, G16, AS_, AD_, nN);
  k_gat<<<(nN * 64 + 255) / 256, 256, 0, stream>>>(G16, rowptr, cntI, eSrc, AS_, AD_, b_g, g3, be3, (float*)d_out, nN);
}

// Round 5
// 280.651 us; speedup vs baseline: 15.7325x; 1.2333x over previous
//
#include <hip/hip_runtime.h>
#include <math.h>

#define EPSV 1e-5f

typedef __attribute__((ext_vector_type(8))) short short8;
typedef __attribute__((ext_vector_type(4))) float f32x4;

__device__ __forceinline__ unsigned short f2b(float f) {
  union { float f; unsigned int u; } c; c.f = f;
  unsigned int u = c.u + 0x7fffu + ((c.u >> 16) & 1u);
  return (unsigned short)(u >> 16);
}
__device__ __forceinline__ float b2f(unsigned short h) {
  union { unsigned int u; float f; } c; c.u = ((unsigned int)h) << 16;
  return c.f;
}

// ---------------------------------------------------------------- weight prep
// WlT[n][k]=bf16(Wl[k][n]) (128x128), WrT same, WgT[n][k]=bf16(Wg[k][n]) (256x128)
__global__ void k_prep(const float* __restrict__ Wl, const float* __restrict__ Wr,
                       const float* __restrict__ Wg, unsigned short* __restrict__ WlT,
                       unsigned short* __restrict__ WrT, unsigned short* __restrict__ WgT) {
  int id = blockIdx.x * 256 + threadIdx.x;  // 0..65535
  if (id < 16384) {
    int n = id >> 7, k = id & 127;
    WlT[id] = f2b(Wl[k * 128 + n]);
  } else if (id < 32768) {
    int j = id - 16384; int n = j >> 7, k = j & 127;
    WrT[j] = f2b(Wr[k * 128 + n]);
  } else {
    int j = id - 32768; int n = j >> 7, k = j & 127;
    WgT[j] = f2b(Wg[k * 256 + n]);
  }
}

// ---------------------------------------------------------------- input proj (bf16 out only)
__global__ void k_proj(const float* __restrict__ x, const float* __restrict__ W,
                       const float* __restrict__ b, unsigned short* __restrict__ h16, int nN) {
  int gid = blockIdx.x * 256 + threadIdx.x;
  if (gid >= nN * 128) return;
  int n = gid >> 7, f = gid & 127;
  const float* xr = x + n * 14;
  float acc = b[f];
#pragma unroll
  for (int k = 0; k < 14; ++k) acc = fmaf(xr[k], W[k * 128 + f], acc);
  h16[gid] = f2b(fmaxf(acc, 0.f));
}

// ---------------------------------------------------------------- degree count
__global__ void k_count_int(const int* __restrict__ dst, int* __restrict__ cnt, int E_) {
  int e = blockIdx.x * 256 + threadIdx.x;
  if (e < E_) atomicAdd(&cnt[dst[e]], 1);
}

// ---------------------------------------------------------------- scan (3-phase)
__global__ void k_scan1(const int* __restrict__ cnt, int* __restrict__ incl,
                        int* __restrict__ bsum, int nN) {
  __shared__ int sh[256];
  int tid = threadIdx.x;
  int i = blockIdx.x * 256 + tid;
  int v = (i < nN) ? cnt[i] : 0;
  sh[tid] = v;
  __syncthreads();
#pragma unroll
  for (int off = 1; off < 256; off <<= 1) {
    int t = (tid >= off) ? sh[tid - off] : 0;
    __syncthreads();
    sh[tid] += t;
    __syncthreads();
  }
  if (i < nN) incl[i] = sh[tid];
  if (tid == 255) bsum[blockIdx.x] = sh[255];
}

__global__ void k_scan2(int* __restrict__ bsum, int nb) {
  __shared__ int sh[256];
  int tid = threadIdx.x;
  int v = (tid < nb) ? bsum[tid] : 0;
  sh[tid] = v;
  __syncthreads();
#pragma unroll
  for (int off = 1; off < 256; off <<= 1) {
    int t = (tid >= off) ? sh[tid - off] : 0;
    __syncthreads();
    sh[tid] += t;
    __syncthreads();
  }
  if (tid < nb) bsum[tid] = sh[tid] - v;  // exclusive
}

__global__ void k_scan3(const int* __restrict__ incl, const int* __restrict__ bsum,
                        const int* __restrict__ cnt, int* __restrict__ rowptr, int nN) {
  int i = blockIdx.x * 256 + threadIdx.x;
  if (i < nN) rowptr[i] = incl[i] - cnt[i] + bsum[blockIdx.x];
}

// ---------------------------------------------------------------- CSR fill
__global__ void k_fill(const int* __restrict__ src, const int* __restrict__ dst,
                       const int* __restrict__ rowptr, int* __restrict__ cursor,
                       int* __restrict__ eSrc, int E_) {
  int e = blockIdx.x * 256 + threadIdx.x;
  if (e >= E_) return;
  int d = dst[e];
  int pos = rowptr[d] + atomicAdd(&cursor[d], 1);
  eSrc[pos] = src[e];
}

// ---------------------------------------------------------------- SAGE gather-mean (bf16, unroll x2)
// 32 lanes/node, 4 feats/lane (ushort4 = 8B)
__global__ void k_sage_gather16(const unsigned short* __restrict__ h16,
                                const int* __restrict__ rowptr, const int* __restrict__ cnt,
                                const int* __restrict__ eSrc,
                                unsigned short* __restrict__ agg16, int nN) {
  int t = blockIdx.x * 256 + threadIdx.x;
  int n = t >> 5;
  if (n >= nN) return;
  int lane = t & 31;
  int beg = rowptr[n], c = cnt[n];
  float ax = 0.f, ay = 0.f, az = 0.f, aw = 0.f;
  float bx = 0.f, by = 0.f, bz = 0.f, bw = 0.f;
  int i = 0;
  for (; i + 2 <= c; i += 2) {
    int s0 = eSrc[beg + i], s1 = eSrc[beg + i + 1];
    ushort4 q0 = *(const ushort4*)(h16 + (size_t)s0 * 128 + lane * 4);
    ushort4 q1 = *(const ushort4*)(h16 + (size_t)s1 * 128 + lane * 4);
    ax += b2f(q0.x); ay += b2f(q0.y); az += b2f(q0.z); aw += b2f(q0.w);
    bx += b2f(q1.x); by += b2f(q1.y); bz += b2f(q1.z); bw += b2f(q1.w);
  }
  if (i < c) {
    int s = eSrc[beg + i];
    ushort4 q = *(const ushort4*)(h16 + (size_t)s * 128 + lane * 4);
    ax += b2f(q.x); ay += b2f(q.y); az += b2f(q.z); aw += b2f(q.w);
  }
  ax += bx; ay += by; az += bz; aw += bw;
  float inv = 1.f / fmaxf((float)c, 1.f);
  ushort4 r;
  r.x = f2b(ax * inv); r.y = f2b(ay * inv); r.z = f2b(az * inv); r.w = f2b(aw * inv);
  *(ushort4*)(agg16 + (size_t)n * 128 + lane * 4) = r;
}

// ---------------------------------------------------------------- SAGE MFMA layer
// Hout16 = bf16( relu(LN([agg|Hin] @ [Wl;Wr] + bias)) + Hin )
__global__ __launch_bounds__(256)
void k_sage_mfma(const unsigned short* __restrict__ agg16,
                 const unsigned short* __restrict__ hin16,
                 const unsigned short* __restrict__ WlT,
                 const unsigned short* __restrict__ WrT,
                 const float* __restrict__ bias, const float* __restrict__ gam,
                 const float* __restrict__ bet,
                 unsigned short* __restrict__ hout16, int nN) {
  __shared__ unsigned short lA[64][136];
  __shared__ unsigned short lB[128][136];
  int tid = threadIdx.x;
  int wave = tid >> 6, lane = tid & 63;
  int cl = lane & 15, g = lane >> 4;
  int rowBase = blockIdx.x * 64;
  f32x4 acc[8];
#pragma unroll
  for (int ct = 0; ct < 8; ++ct) acc[ct] = (f32x4){0.f, 0.f, 0.f, 0.f};

  int ar = tid >> 2, ap = (tid & 3) * 32;  // A stage: row, k-part
  int br = tid >> 1, bp = (tid & 1) * 64;  // B stage: row, k-part

  for (int half = 0; half < 2; ++half) {
    const unsigned short* At = half ? hin16 : agg16;
    const unsigned short* Bt = half ? WrT : WlT;
    if (half) __syncthreads();
    {
      int grow = rowBase + ar;
      if (grow < nN) {
        const unsigned short* sp = At + (size_t)grow * 128 + ap;
#pragma unroll
        for (int u = 0; u < 4; ++u)
          *(short8*)&lA[ar][ap + u * 8] = *(const short8*)(sp + u * 8);
      } else {
        short8 z = {0, 0, 0, 0, 0, 0, 0, 0};
#pragma unroll
        for (int u = 0; u < 4; ++u) *(short8*)&lA[ar][ap + u * 8] = z;
      }
      const unsigned short* bsp = Bt + (size_t)br * 128 + bp;
#pragma unroll
      for (int u = 0; u < 8; ++u)
        *(short8*)&lB[br][bp + u * 8] = *(const short8*)(bsp + u * 8);
    }
    __syncthreads();
#pragma unroll
    for (int ks = 0; ks < 4; ++ks) {
      short8 a = *(const short8*)&lA[wave * 16 + cl][ks * 32 + g * 8];
#pragma unroll
      for (int ct = 0; ct < 8; ++ct) {
        short8 b = *(const short8*)&lB[ct * 16 + cl][ks * 32 + g * 8];
        acc[ct] = __builtin_amdgcn_mfma_f32_16x16x32_bf16(a, b, acc[ct], 0, 0, 0);
      }
    }
  }
  __syncthreads();

  // epilogue: +bias, LN over 128 cols, *gam+bet, relu, +residual(bf16)
  float bcol[8], gcol[8], ecol[8];
#pragma unroll
  for (int ct = 0; ct < 8; ++ct) {
    int c = ct * 16 + cl;
    bcol[ct] = bias[c]; gcol[ct] = gam[c]; ecol[ct] = bet[c];
  }
  float v[8][4];
  float s1[4] = {0.f, 0.f, 0.f, 0.f}, s2[4] = {0.f, 0.f, 0.f, 0.f};
#pragma unroll
  for (int ct = 0; ct < 8; ++ct)
#pragma unroll
    for (int r = 0; r < 4; ++r) {
      float t = acc[ct][r] + bcol[ct];
      v[ct][r] = t;
      s1[r] += t; s2[r] += t * t;
    }
#pragma unroll
  for (int m = 1; m <= 8; m <<= 1)
#pragma unroll
    for (int r = 0; r < 4; ++r) { s1[r] += __shfl_xor(s1[r], m); s2[r] += __shfl_xor(s2[r], m); }

#pragma unroll
  for (int r = 0; r < 4; ++r) {
    float mean = s1[r] * (1.f / 128.f);
    float var = s2[r] * (1.f / 128.f) - mean * mean;
    float rstd = rsqrtf(var + EPSV);
    int grow = rowBase + wave * 16 + g * 4 + r;
    if (grow < nN) {
#pragma unroll
      for (int ct = 0; ct < 8; ++ct) {
        int c = ct * 16 + cl;
        float o = fmaxf((v[ct][r] - mean) * rstd * gcol[ct] + ecol[ct], 0.f)
                  + b2f(hin16[(size_t)grow * 128 + c]);
        hout16[(size_t)grow * 128 + c] = f2b(o);
      }
    }
  }
}

// ---------------------------------------------------------------- GAT GEMM (MFMA) + logits
// G[:,y*128..y*128+127] = h @ Wg[:, half y]; logits for heads 2y, 2y+1
__global__ __launch_bounds__(256)
void k_gatgemm(const unsigned short* __restrict__ h16, const unsigned short* __restrict__ WgT,
               const float* __restrict__ atts, const float* __restrict__ attd,
               unsigned short* __restrict__ G16, float* __restrict__ as_,
               float* __restrict__ ad_, int nN) {
  __shared__ unsigned short lA[64][136];
  __shared__ unsigned short lB[128][136];
  int tid = threadIdx.x;
  int wave = tid >> 6, lane = tid & 63;
  int cl = lane & 15, g = lane >> 4;
  int rowBase = blockIdx.x * 64;
  int y = blockIdx.y;
  f32x4 acc[8];
#pragma unroll
  for (int ct = 0; ct < 8; ++ct) acc[ct] = (f32x4){0.f, 0.f, 0.f, 0.f};

  int ar = tid >> 2, ap = (tid & 3) * 32;
  int br = tid >> 1, bp = (tid & 1) * 64;
  {
    int grow = rowBase + ar;
    if (grow < nN) {
      const unsigned short* sp = h16 + (size_t)grow * 128 + ap;
#pragma unroll
      for (int u = 0; u < 4; ++u)
        *(short8*)&lA[ar][ap + u * 8] = *(const short8*)(sp + u * 8);
    } else {
      short8 z = {0, 0, 0, 0, 0, 0, 0, 0};
#pragma unroll
      for (int u = 0; u < 4; ++u) *(short8*)&lA[ar][ap + u * 8] = z;
    }
    const unsigned short* bsp = WgT + (size_t)(y * 128 + br) * 128 + bp;
#pragma unroll
    for (int u = 0; u < 8; ++u)
      *(short8*)&lB[br][bp + u * 8] = *(const short8*)(bsp + u * 8);
  }
  __syncthreads();
#pragma unroll
  for (int ks = 0; ks < 4; ++ks) {
    short8 a = *(const short8*)&lA[wave * 16 + cl][ks * 32 + g * 8];
#pragma unroll
    for (int ct = 0; ct < 8; ++ct) {
      short8 b = *(const short8*)&lB[ct * 16 + cl][ks * 32 + g * 8];
      acc[ct] = __builtin_amdgcn_mfma_f32_16x16x32_bf16(a, b, acc[ct], 0, 0, 0);
    }
  }

  // epilogue: store G16 + attention logits for heads 2y+hh (hh = ct>>2)
  float atr[8], adr[8];
#pragma unroll
  for (int ct = 0; ct < 8; ++ct) {
    int h = y * 2 + (ct >> 2);
    int w = (ct & 3) * 16 + cl;  // col within head
    atr[ct] = atts[h * 64 + w];
    adr[ct] = attd[h * 64 + w];
  }
  float ps[2][4], pd[2][4];
#pragma unroll
  for (int hh = 0; hh < 2; ++hh)
#pragma unroll
    for (int r = 0; r < 4; ++r) { ps[hh][r] = 0.f; pd[hh][r] = 0.f; }

#pragma unroll
  for (int r = 0; r < 4; ++r) {
    int grow = rowBase + wave * 16 + g * 4 + r;
    if (grow < nN) {
      unsigned short* op = G16 + (size_t)grow * 256 + y * 128 + cl;
#pragma unroll
      for (int ct = 0; ct < 8; ++ct) op[ct * 16] = f2b(acc[ct][r]);
    }
#pragma unroll
    for (int ct = 0; ct < 8; ++ct) {
      ps[ct >> 2][r] = fmaf(acc[ct][r], atr[ct], ps[ct >> 2][r]);
      pd[ct >> 2][r] = fmaf(acc[ct][r], adr[ct], pd[ct >> 2][r]);
    }
  }
#pragma unroll
  for (int m = 1; m <= 8; m <<= 1)
#pragma unroll
    for (int hh = 0; hh < 2; ++hh)
#pragma unroll
      for (int r = 0; r < 4; ++r) {
        ps[hh][r] += __shfl_xor(ps[hh][r], m);
        pd[hh][r] += __shfl_xor(pd[hh][r], m);
      }
  if (cl == 0) {
#pragma unroll
    for (int r = 0; r < 4; ++r) {
      int grow = rowBase + wave * 16 + g * 4 + r;
      if (grow < nN) {
#pragma unroll
        for (int hh = 0; hh < 2; ++hh) {
          as_[grow * 4 + y * 2 + hh] = ps[hh][r];
          ad_[grow * 4 + y * 2 + hh] = pd[hh][r];
        }
      }
    }
  }
}

// ---------------------------------------------------------------- fused GAT gather + LN
// 64 lanes/node; unroll x2; leaky=max(x,0.2x); native exp
__global__ void k_gat(const unsigned short* __restrict__ G16, const int* __restrict__ rowptr,
                      const int* __restrict__ cnt, const int* __restrict__ eSrc,
                      const float* __restrict__ as_, const float* __restrict__ ad_,
                      const float* __restrict__ bg, const float* __restrict__ g3,
                      const float* __restrict__ be3, float* __restrict__ out, int nN) {
  int t = blockIdx.x * 256 + threadIdx.x;
  int n = t >> 6;
  if (n >= nN) return;
  int lane = t & 63;
  int h = lane >> 4;
  float adn = ad_[n * 4 + h];

  // self loop
  float e0 = as_[n * 4 + h] + adn;
  e0 = fmaxf(e0, 0.2f * e0);
  float w = __expf(e0);
  ushort4 q = *(const ushort4*)(G16 + (size_t)n * 256 + lane * 4);
  float ax = w * b2f(q.x), ay = w * b2f(q.y), az = w * b2f(q.z), aw = w * b2f(q.w);
  float den = w;
  float bx = 0.f, by = 0.f, bz = 0.f, bw = 0.f, den2 = 0.f;

  int beg = rowptr[n], c = cnt[n];
  int i = 0;
  for (; i + 2 <= c; i += 2) {
    int s0 = eSrc[beg + i], s1 = eSrc[beg + i + 1];
    float ev0 = as_[s0 * 4 + h] + adn;
    float ev1 = as_[s1 * 4 + h] + adn;
    ev0 = fmaxf(ev0, 0.2f * ev0);
    ev1 = fmaxf(ev1, 0.2f * ev1);
    float w0 = __expf(ev0), w1 = __expf(ev1);
    ushort4 q0 = *(const ushort4*)(G16 + (size_t)s0 * 256 + lane * 4);
    ushort4 q1 = *(const ushort4*)(G16 + (size_t)s1 * 256 + lane * 4);
    ax = fmaf(w0, b2f(q0.x), ax); ay = fmaf(w0, b2f(q0.y), ay);
    az = fmaf(w0, b2f(q0.z), az); aw = fmaf(w0, b2f(q0.w), aw);
    bx = fmaf(w1, b2f(q1.x), bx); by = fmaf(w1, b2f(q1.y), by);
    bz = fmaf(w1, b2f(q1.z), bz); bw = fmaf(w1, b2f(q1.w), bw);
    den += w0; den2 += w1;
  }
  if (i < c) {
    int s = eSrc[beg + i];
    float ev = as_[s * 4 + h] + adn;
    ev = fmaxf(ev, 0.2f * ev);
    w = __expf(ev);
    q = *(const ushort4*)(G16 + (size_t)s * 256 + lane * 4);
    ax = fmaf(w, b2f(q.x), ax); ay = fmaf(w, b2f(q.y), ay);
    az = fmaf(w, b2f(q.z), az); aw = fmaf(w, b2f(q.w), aw);
    den += w;
  }
  ax += bx; ay += by; az += bz; aw += bw;
  den += den2;

  float inv = 1.f / den;
  ax *= inv; ay *= inv; az *= inv; aw *= inv;

  // head-mean over lane bits 4,5
#pragma unroll
  for (int m = 32; m >= 16; m >>= 1) {
    ax += __shfl_xor(ax, m); ay += __shfl_xor(ay, m);
    az += __shfl_xor(az, m); aw += __shfl_xor(aw, m);
  }
  int fb = (lane & 15) * 4;
  float v0 = ax * 0.25f + bg[fb];
  float v1 = ay * 0.25f + bg[fb + 1];
  float v2 = az * 0.25f + bg[fb + 2];
  float v3 = aw * 0.25f + bg[fb + 3];

  float s1 = v0 + v1 + v2 + v3;
  float s2 = v0 * v0 + v1 * v1 + v2 * v2 + v3 * v3;
#pragma unroll
  for (int m = 8; m >= 1; m >>= 1) { s1 += __shfl_xor(s1, m); s2 += __shfl_xor(s2, m); }
  float mean = s1 * (1.f / 64.f);
  float var = s2 * (1.f / 64.f) - mean * mean;
  float rstd = rsqrtf(var + EPSV);
  if ((lane >> 4) == 0) {
    float4 o;
    o.x = (v0 - mean) * rstd * g3[fb] + be3[fb];
    o.y = (v1 - mean) * rstd * g3[fb + 1] + be3[fb + 1];
    o.z = (v2 - mean) * rstd * g3[fb + 2] + be3[fb + 2];
    o.w = (v3 - mean) * rstd * g3[fb + 3] + be3[fb + 3];
    *(float4*)(out + (size_t)n * 64 + fb) = o;
  }
}

// ================================================================ launch
extern "C" void kernel_launch(void* const* d_in, const int* in_sizes, int n_in,
                              void* d_out, int out_size, void* d_ws, size_t ws_size,
                              hipStream_t stream) {
  const float* x    = (const float*)d_in[0];
  const int*   edge = (const int*)d_in[1];
  const float* W_in = (const float*)d_in[2];
  const float* b_in = (const float*)d_in[3];
  const float* W1_l = (const float*)d_in[4];
  const float* b1   = (const float*)d_in[5];
  const float* W1_r = (const float*)d_in[6];
  const float* g1   = (const float*)d_in[7];
  const float* be1  = (const float*)d_in[8];
  const float* W2_l = (const float*)d_in[9];
  const float* b2   = (const float*)d_in[10];
  const float* W2_r = (const float*)d_in[11];
  const float* g2   = (const float*)d_in[12];
  const float* be2  = (const float*)d_in[13];
  const float* W_g  = (const float*)d_in[14];
  const float* atts = (const float*)d_in[15];
  const float* attd = (const float*)d_in[16];
  const float* b_g  = (const float*)d_in[17];
  const float* g3   = (const float*)d_in[18];
  const float* be3  = (const float*)d_in[19];

  const int nN = in_sizes[0] / 14;
  const int E_ = in_sizes[1] / 2;
  const int* src = edge;
  const int* dst = edge + E_;

  char* W = (char*)d_ws;
  unsigned short* hA16  = (unsigned short*)W; W += (size_t)nN * 128 * 2;
  unsigned short* hB16  = (unsigned short*)W; W += (size_t)nN * 128 * 2;
  unsigned short* agg16 = (unsigned short*)W; W += (size_t)nN * 128 * 2;
  unsigned short* G16   = (unsigned short*)W; W += (size_t)nN * 256 * 2;
  unsigned short* WlT   = (unsigned short*)W; W += 16384 * 2;
  unsigned short* WrT   = (unsigned short*)W; W += 16384 * 2;
  unsigned short* WgT   = (unsigned short*)W; W += 32768 * 2;
  float* AS_ = (float*)W;                W += (size_t)nN * 4 * 4;
  float* AD_ = (float*)W;                W += (size_t)nN * 4 * 4;
  int* cntI   = (int*)W;                 W += (size_t)nN * 4;
  int* rowptr = (int*)W;                 W += (size_t)nN * 4;
  int* cursor = (int*)W;                 W += (size_t)nN * 4;
  int* incl   = (int*)W;                 W += (size_t)nN * 4;
  int* bsum   = (int*)W;                 W += 1024 * 4;
  int* eSrc   = (int*)W;

  const int SB = (nN + 255) / 256;  // 196 for N=50000 (must be <=256)
  const int NB = (nN + 63) / 64;

  hipMemsetAsync(cntI, 0, (size_t)nN * sizeof(int), stream);
  hipMemsetAsync(cursor, 0, (size_t)nN * sizeof(int), stream);

  // CSR by dst
  k_count_int<<<(E_ + 255) / 256, 256, 0, stream>>>(dst, cntI, E_);
  k_scan1<<<SB, 256, 0, stream>>>(cntI, incl, bsum, nN);
  k_scan2<<<1, 256, 0, stream>>>(bsum, SB);
  k_scan3<<<SB, 256, 0, stream>>>(incl, bsum, cntI, rowptr, nN);
  k_fill<<<(E_ + 255) / 256, 256, 0, stream>>>(src, dst, rowptr, cursor, eSrc, E_);

  // weight prep + input projection
  k_prep<<<256, 256, 0, stream>>>(W1_l, W1_r, W_g, WlT, WrT, WgT);
  k_proj<<<(nN * 128 + 255) / 256, 256, 0, stream>>>(x, W_in, b_in, hA16, nN);

  // SAGE layer 1: hA16 -> hB16
  k_sage_gather16<<<(nN * 32 + 255) / 256, 256, 0, stream>>>(hA16, rowptr, cntI, eSrc, agg16, nN);
  k_sage_mfma<<<NB, 256, 0, stream>>>(agg16, hA16, WlT, WrT, b1, g1, be1, hB16, nN);

  // SAGE layer 2: hB16 -> hA16   (re-prep: WlT/WrT now layer-2 weights)
  k_prep<<<256, 256, 0, stream>>>(W2_l, W2_r, W_g, WlT, WrT, WgT);
  k_sage_gather16<<<(nN * 32 + 255) / 256, 256, 0, stream>>>(hB16, rowptr, cntI, eSrc, agg16, nN);
  k_sage_mfma<<<NB, 256, 0, stream>>>(agg16, hB16, WlT, WrT, b2, g2, be2, hA16, nN);

  // GAT: hA16 -> G16 (+logits) -> out
  k_gatgemm<<<dim3(NB, 2), 256, 0, stream>>>(hA16, WgT, atts, attd, G16, AS_, AD_, nN);
  k_gat<<<(nN * 64 + 255) / 256, 256, 0, stream>>>(G16, rowptr, cntI, eSrc, AS_, AD_, b_g, g3, be3, (float*)d_out, nN);
}

// Round 6
// 268.826 us; speedup vs baseline: 16.4245x; 1.0440x over previous
//
#include <hip/hip_runtime.h>
#include <math.h>

#define EPSV 1e-5f

typedef __attribute__((ext_vector_type(8))) short short8;
typedef __attribute__((ext_vector_type(4))) float f32x4;

__device__ __forceinline__ unsigned short f2b(float f) {
  union { float f; unsigned int u; } c; c.f = f;
  unsigned int u = c.u + 0x7fffu + ((c.u >> 16) & 1u);
  return (unsigned short)(u >> 16);
}
__device__ __forceinline__ float b2f(unsigned short h) {
  union { unsigned int u; float f; } c; c.u = ((unsigned int)h) << 16;
  return c.f;
}

// ---------------------------------------------------------------- weight prep
// layer1: WlT/WrT (128x128 each) + WgT (256x128)
__global__ void k_prep3(const float* __restrict__ Wl, const float* __restrict__ Wr,
                        const float* __restrict__ Wg, unsigned short* __restrict__ WlT,
                        unsigned short* __restrict__ WrT, unsigned short* __restrict__ WgT) {
  int id = blockIdx.x * 256 + threadIdx.x;  // 0..65535
  if (id < 16384) {
    int n = id >> 7, k = id & 127;
    WlT[id] = f2b(Wl[k * 128 + n]);
  } else if (id < 32768) {
    int j = id - 16384; int n = j >> 7, k = j & 127;
    WrT[j] = f2b(Wr[k * 128 + n]);
  } else {
    int j = id - 32768; int n = j >> 7, k = j & 127;
    WgT[j] = f2b(Wg[k * 256 + n]);
  }
}
// layer2: only Wl/Wr
__global__ void k_prep2(const float* __restrict__ Wl, const float* __restrict__ Wr,
                        unsigned short* __restrict__ WlT, unsigned short* __restrict__ WrT) {
  int id = blockIdx.x * 256 + threadIdx.x;  // 0..32767
  if (id < 16384) {
    int n = id >> 7, k = id & 127;
    WlT[id] = f2b(Wl[k * 128 + n]);
  } else {
    int j = id - 16384; int n = j >> 7, k = j & 127;
    WrT[j] = f2b(Wr[k * 128 + n]);
  }
}

// ---------------------------------------------------------------- input proj (bf16 out only)
__global__ void k_proj(const float* __restrict__ x, const float* __restrict__ W,
                       const float* __restrict__ b, unsigned short* __restrict__ h16, int nN) {
  int gid = blockIdx.x * 256 + threadIdx.x;
  if (gid >= nN * 128) return;
  int n = gid >> 7, f = gid & 127;
  const float* xr = x + n * 14;
  float acc = b[f];
#pragma unroll
  for (int k = 0; k < 14; ++k) acc = fmaf(xr[k], W[k * 128 + f], acc);
  h16[gid] = f2b(fmaxf(acc, 0.f));
}

// ---------------------------------------------------------------- degree count
__global__ void k_count_int(const int* __restrict__ dst, int* __restrict__ cnt, int E_) {
  int e = blockIdx.x * 256 + threadIdx.x;
  if (e < E_) atomicAdd(&cnt[dst[e]], 1);
}

// ---------------------------------------------------------------- scan (3-phase)
__global__ void k_scan1(const int* __restrict__ cnt, int* __restrict__ incl,
                        int* __restrict__ bsum, int nN) {
  __shared__ int sh[256];
  int tid = threadIdx.x;
  int i = blockIdx.x * 256 + tid;
  int v = (i < nN) ? cnt[i] : 0;
  sh[tid] = v;
  __syncthreads();
#pragma unroll
  for (int off = 1; off < 256; off <<= 1) {
    int t = (tid >= off) ? sh[tid - off] : 0;
    __syncthreads();
    sh[tid] += t;
    __syncthreads();
  }
  if (i < nN) incl[i] = sh[tid];
  if (tid == 255) bsum[blockIdx.x] = sh[255];
}

__global__ void k_scan2(int* __restrict__ bsum, int nb) {
  __shared__ int sh[256];
  int tid = threadIdx.x;
  int v = (tid < nb) ? bsum[tid] : 0;
  sh[tid] = v;
  __syncthreads();
#pragma unroll
  for (int off = 1; off < 256; off <<= 1) {
    int t = (tid >= off) ? sh[tid - off] : 0;
    __syncthreads();
    sh[tid] += t;
    __syncthreads();
  }
  if (tid < nb) bsum[tid] = sh[tid] - v;  // exclusive
}

__global__ void k_scan3(const int* __restrict__ incl, const int* __restrict__ bsum,
                        const int* __restrict__ cnt, int* __restrict__ rowptr, int nN) {
  int i = blockIdx.x * 256 + threadIdx.x;
  if (i < nN) rowptr[i] = incl[i] - cnt[i] + bsum[blockIdx.x];
}

// ---------------------------------------------------------------- CSR fill
__global__ void k_fill(const int* __restrict__ src, const int* __restrict__ dst,
                       const int* __restrict__ rowptr, int* __restrict__ cursor,
                       int* __restrict__ eSrc, int E_) {
  int e = blockIdx.x * 256 + threadIdx.x;
  if (e >= E_) return;
  int d = dst[e];
  int pos = rowptr[d] + atomicAdd(&cursor[d], 1);
  eSrc[pos] = src[e];
}

// ---------------------------------------------------------------- SAGE gather-mean (bf16, unroll x4)
// 32 lanes/node, 4 feats/lane (ushort4 = 8B); 4 independent accumulator banks
__global__ void k_sage_gather16(const unsigned short* __restrict__ h16,
                                const int* __restrict__ rowptr, const int* __restrict__ cnt,
                                const int* __restrict__ eSrc,
                                unsigned short* __restrict__ agg16, int nN) {
  int t = blockIdx.x * 256 + threadIdx.x;
  int n = t >> 5;
  if (n >= nN) return;
  int lane = t & 31;
  int beg = rowptr[n], c = cnt[n];
  float a0x = 0.f, a0y = 0.f, a0z = 0.f, a0w = 0.f;
  float a1x = 0.f, a1y = 0.f, a1z = 0.f, a1w = 0.f;
  float a2x = 0.f, a2y = 0.f, a2z = 0.f, a2w = 0.f;
  float a3x = 0.f, a3y = 0.f, a3z = 0.f, a3w = 0.f;
  int i = 0;
  for (; i + 4 <= c; i += 4) {
    int s0 = eSrc[beg + i], s1 = eSrc[beg + i + 1];
    int s2 = eSrc[beg + i + 2], s3 = eSrc[beg + i + 3];
    ushort4 q0 = *(const ushort4*)(h16 + (size_t)s0 * 128 + lane * 4);
    ushort4 q1 = *(const ushort4*)(h16 + (size_t)s1 * 128 + lane * 4);
    ushort4 q2 = *(const ushort4*)(h16 + (size_t)s2 * 128 + lane * 4);
    ushort4 q3 = *(const ushort4*)(h16 + (size_t)s3 * 128 + lane * 4);
    a0x += b2f(q0.x); a0y += b2f(q0.y); a0z += b2f(q0.z); a0w += b2f(q0.w);
    a1x += b2f(q1.x); a1y += b2f(q1.y); a1z += b2f(q1.z); a1w += b2f(q1.w);
    a2x += b2f(q2.x); a2y += b2f(q2.y); a2z += b2f(q2.z); a2w += b2f(q2.w);
    a3x += b2f(q3.x); a3y += b2f(q3.y); a3z += b2f(q3.z); a3w += b2f(q3.w);
  }
  for (; i < c; ++i) {
    int s = eSrc[beg + i];
    ushort4 q = *(const ushort4*)(h16 + (size_t)s * 128 + lane * 4);
    a0x += b2f(q.x); a0y += b2f(q.y); a0z += b2f(q.z); a0w += b2f(q.w);
  }
  float ax = (a0x + a1x) + (a2x + a3x);
  float ay = (a0y + a1y) + (a2y + a3y);
  float az = (a0z + a1z) + (a2z + a3z);
  float aw = (a0w + a1w) + (a2w + a3w);
  float inv = 1.f / fmaxf((float)c, 1.f);
  ushort4 r;
  r.x = f2b(ax * inv); r.y = f2b(ay * inv); r.z = f2b(az * inv); r.w = f2b(aw * inv);
  *(ushort4*)(agg16 + (size_t)n * 128 + lane * 4) = r;
}

// ---------------------------------------------------------------- SAGE MFMA layer
// Hout16 = bf16( relu(LN([agg|Hin] @ [Wl;Wr] + bias)) + Hin )
__global__ __launch_bounds__(256)
void k_sage_mfma(const unsigned short* __restrict__ agg16,
                 const unsigned short* __restrict__ hin16,
                 const unsigned short* __restrict__ WlT,
                 const unsigned short* __restrict__ WrT,
                 const float* __restrict__ bias, const float* __restrict__ gam,
                 const float* __restrict__ bet,
                 unsigned short* __restrict__ hout16, int nN) {
  __shared__ unsigned short lA[64][136];
  __shared__ unsigned short lB[128][136];
  int tid = threadIdx.x;
  int wave = tid >> 6, lane = tid & 63;
  int cl = lane & 15, g = lane >> 4;
  int rowBase = blockIdx.x * 64;
  f32x4 acc[8];
#pragma unroll
  for (int ct = 0; ct < 8; ++ct) acc[ct] = (f32x4){0.f, 0.f, 0.f, 0.f};

  int ar = tid >> 2, ap = (tid & 3) * 32;  // A stage: row, k-part
  int br = tid >> 1, bp = (tid & 1) * 64;  // B stage: row, k-part

  for (int half = 0; half < 2; ++half) {
    const unsigned short* At = half ? hin16 : agg16;
    const unsigned short* Bt = half ? WrT : WlT;
    if (half) __syncthreads();
    {
      int grow = rowBase + ar;
      if (grow < nN) {
        const unsigned short* sp = At + (size_t)grow * 128 + ap;
#pragma unroll
        for (int u = 0; u < 4; ++u)
          *(short8*)&lA[ar][ap + u * 8] = *(const short8*)(sp + u * 8);
      } else {
        short8 z = {0, 0, 0, 0, 0, 0, 0, 0};
#pragma unroll
        for (int u = 0; u < 4; ++u) *(short8*)&lA[ar][ap + u * 8] = z;
      }
      const unsigned short* bsp = Bt + (size_t)br * 128 + bp;
#pragma unroll
      for (int u = 0; u < 8; ++u)
        *(short8*)&lB[br][bp + u * 8] = *(const short8*)(bsp + u * 8);
    }
    __syncthreads();
#pragma unroll
    for (int ks = 0; ks < 4; ++ks) {
      short8 a = *(const short8*)&lA[wave * 16 + cl][ks * 32 + g * 8];
#pragma unroll
      for (int ct = 0; ct < 8; ++ct) {
        short8 b = *(const short8*)&lB[ct * 16 + cl][ks * 32 + g * 8];
        acc[ct] = __builtin_amdgcn_mfma_f32_16x16x32_bf16(a, b, acc[ct], 0, 0, 0);
      }
    }
  }
  __syncthreads();

  // epilogue: +bias, LN over 128 cols, *gam+bet, relu, +residual(bf16)
  float bcol[8], gcol[8], ecol[8];
#pragma unroll
  for (int ct = 0; ct < 8; ++ct) {
    int c = ct * 16 + cl;
    bcol[ct] = bias[c]; gcol[ct] = gam[c]; ecol[ct] = bet[c];
  }
  float v[8][4];
  float s1[4] = {0.f, 0.f, 0.f, 0.f}, s2[4] = {0.f, 0.f, 0.f, 0.f};
#pragma unroll
  for (int ct = 0; ct < 8; ++ct)
#pragma unroll
    for (int r = 0; r < 4; ++r) {
      float t = acc[ct][r] + bcol[ct];
      v[ct][r] = t;
      s1[r] += t; s2[r] += t * t;
    }
#pragma unroll
  for (int m = 1; m <= 8; m <<= 1)
#pragma unroll
    for (int r = 0; r < 4; ++r) { s1[r] += __shfl_xor(s1[r], m); s2[r] += __shfl_xor(s2[r], m); }

#pragma unroll
  for (int r = 0; r < 4; ++r) {
    float mean = s1[r] * (1.f / 128.f);
    float var = s2[r] * (1.f / 128.f) - mean * mean;
    float rstd = rsqrtf(var + EPSV);
    int grow = rowBase + wave * 16 + g * 4 + r;
    if (grow < nN) {
#pragma unroll
      for (int ct = 0; ct < 8; ++ct) {
        int c = ct * 16 + cl;
        float o = fmaxf((v[ct][r] - mean) * rstd * gcol[ct] + ecol[ct], 0.f)
                  + b2f(hin16[(size_t)grow * 128 + c]);
        hout16[(size_t)grow * 128 + c] = f2b(o);
      }
    }
  }
}

// ---------------------------------------------------------------- GAT GEMM (MFMA) + logits
// G[:,y*128..y*128+127] = h @ Wg[:, half y]; logits for heads 2y, 2y+1
__global__ __launch_bounds__(256)
void k_gatgemm(const unsigned short* __restrict__ h16, const unsigned short* __restrict__ WgT,
               const float* __restrict__ atts, const float* __restrict__ attd,
               unsigned short* __restrict__ G16, float* __restrict__ as_,
               float* __restrict__ ad_, int nN) {
  __shared__ unsigned short lA[64][136];
  __shared__ unsigned short lB[128][136];
  int tid = threadIdx.x;
  int wave = tid >> 6, lane = tid & 63;
  int cl = lane & 15, g = lane >> 4;
  int rowBase = blockIdx.x * 64;
  int y = blockIdx.y;
  f32x4 acc[8];
#pragma unroll
  for (int ct = 0; ct < 8; ++ct) acc[ct] = (f32x4){0.f, 0.f, 0.f, 0.f};

  int ar = tid >> 2, ap = (tid & 3) * 32;
  int br = tid >> 1, bp = (tid & 1) * 64;
  {
    int grow = rowBase + ar;
    if (grow < nN) {
      const unsigned short* sp = h16 + (size_t)grow * 128 + ap;
#pragma unroll
      for (int u = 0; u < 4; ++u)
        *(short8*)&lA[ar][ap + u * 8] = *(const short8*)(sp + u * 8);
    } else {
      short8 z = {0, 0, 0, 0, 0, 0, 0, 0};
#pragma unroll
      for (int u = 0; u < 4; ++u) *(short8*)&lA[ar][ap + u * 8] = z;
    }
    const unsigned short* bsp = WgT + (size_t)(y * 128 + br) * 128 + bp;
#pragma unroll
    for (int u = 0; u < 8; ++u)
      *(short8*)&lB[br][bp + u * 8] = *(const short8*)(bsp + u * 8);
  }
  __syncthreads();
#pragma unroll
  for (int ks = 0; ks < 4; ++ks) {
    short8 a = *(const short8*)&lA[wave * 16 + cl][ks * 32 + g * 8];
#pragma unroll
    for (int ct = 0; ct < 8; ++ct) {
      short8 b = *(const short8*)&lB[ct * 16 + cl][ks * 32 + g * 8];
      acc[ct] = __builtin_amdgcn_mfma_f32_16x16x32_bf16(a, b, acc[ct], 0, 0, 0);
    }
  }

  // epilogue: store G16 + attention logits for heads 2y+hh (hh = ct>>2)
  float atr[8], adr[8];
#pragma unroll
  for (int ct = 0; ct < 8; ++ct) {
    int h = y * 2 + (ct >> 2);
    int w = (ct & 3) * 16 + cl;  // col within head
    atr[ct] = atts[h * 64 + w];
    adr[ct] = attd[h * 64 + w];
  }
  float ps[2][4], pd[2][4];
#pragma unroll
  for (int hh = 0; hh < 2; ++hh)
#pragma unroll
    for (int r = 0; r < 4; ++r) { ps[hh][r] = 0.f; pd[hh][r] = 0.f; }

#pragma unroll
  for (int r = 0; r < 4; ++r) {
    int grow = rowBase + wave * 16 + g * 4 + r;
    if (grow < nN) {
      unsigned short* op = G16 + (size_t)grow * 256 + y * 128 + cl;
#pragma unroll
      for (int ct = 0; ct < 8; ++ct) op[ct * 16] = f2b(acc[ct][r]);
    }
#pragma unroll
    for (int ct = 0; ct < 8; ++ct) {
      ps[ct >> 2][r] = fmaf(acc[ct][r], atr[ct], ps[ct >> 2][r]);
      pd[ct >> 2][r] = fmaf(acc[ct][r], adr[ct], pd[ct >> 2][r]);
    }
  }
#pragma unroll
  for (int m = 1; m <= 8; m <<= 1)
#pragma unroll
    for (int hh = 0; hh < 2; ++hh)
#pragma unroll
      for (int r = 0; r < 4; ++r) {
        ps[hh][r] += __shfl_xor(ps[hh][r], m);
        pd[hh][r] += __shfl_xor(pd[hh][r], m);
      }
  if (cl == 0) {
#pragma unroll
    for (int r = 0; r < 4; ++r) {
      int grow = rowBase + wave * 16 + g * 4 + r;
      if (grow < nN) {
#pragma unroll
        for (int hh = 0; hh < 2; ++hh) {
          as_[grow * 4 + y * 2 + hh] = ps[hh][r];
          ad_[grow * 4 + y * 2 + hh] = pd[hh][r];
        }
      }
    }
  }
}

// ---------------------------------------------------------------- fused GAT gather + LN
// 64 lanes/node; unroll x4 (4 accumulator banks); leaky=max(x,0.2x); native exp
__global__ void k_gat(const unsigned short* __restrict__ G16, const int* __restrict__ rowptr,
                      const int* __restrict__ cnt, const int* __restrict__ eSrc,
                      const float* __restrict__ as_, const float* __restrict__ ad_,
                      const float* __restrict__ bg, const float* __restrict__ g3,
                      const float* __restrict__ be3, float* __restrict__ out, int nN) {
  int t = blockIdx.x * 256 + threadIdx.x;
  int n = t >> 6;
  if (n >= nN) return;
  int lane = t & 63;
  int h = lane >> 4;
  float adn = ad_[n * 4 + h];

  // self loop -> bank 0
  float e0 = as_[n * 4 + h] + adn;
  e0 = fmaxf(e0, 0.2f * e0);
  float w = __expf(e0);
  ushort4 q = *(const ushort4*)(G16 + (size_t)n * 256 + lane * 4);
  float a0x = w * b2f(q.x), a0y = w * b2f(q.y), a0z = w * b2f(q.z), a0w = w * b2f(q.w);
  float d0 = w;
  float a1x = 0.f, a1y = 0.f, a1z = 0.f, a1w = 0.f, d1 = 0.f;
  float a2x = 0.f, a2y = 0.f, a2z = 0.f, a2w = 0.f, d2 = 0.f;
  float a3x = 0.f, a3y = 0.f, a3z = 0.f, a3w = 0.f, d3 = 0.f;

  int beg = rowptr[n], c = cnt[n];
  int i = 0;
  for (; i + 4 <= c; i += 4) {
    int s0 = eSrc[beg + i], s1 = eSrc[beg + i + 1];
    int s2 = eSrc[beg + i + 2], s3 = eSrc[beg + i + 3];
    float ev0 = as_[s0 * 4 + h] + adn;
    float ev1 = as_[s1 * 4 + h] + adn;
    float ev2 = as_[s2 * 4 + h] + adn;
    float ev3 = as_[s3 * 4 + h] + adn;
    ev0 = fmaxf(ev0, 0.2f * ev0); ev1 = fmaxf(ev1, 0.2f * ev1);
    ev2 = fmaxf(ev2, 0.2f * ev2); ev3 = fmaxf(ev3, 0.2f * ev3);
    float w0 = __expf(ev0), w1 = __expf(ev1), w2 = __expf(ev2), w3 = __expf(ev3);
    ushort4 q0 = *(const ushort4*)(G16 + (size_t)s0 * 256 + lane * 4);
    ushort4 q1 = *(const ushort4*)(G16 + (size_t)s1 * 256 + lane * 4);
    ushort4 q2 = *(const ushort4*)(G16 + (size_t)s2 * 256 + lane * 4);
    ushort4 q3 = *(const ushort4*)(G16 + (size_t)s3 * 256 + lane * 4);
    a0x = fmaf(w0, b2f(q0.x), a0x); a0y = fmaf(w0, b2f(q0.y), a0y);
    a0z = fmaf(w0, b2f(q0.z), a0z); a0w = fmaf(w0, b2f(q0.w), a0w);
    a1x = fmaf(w1, b2f(q1.x), a1x); a1y = fmaf(w1, b2f(q1.y), a1y);
    a1z = fmaf(w1, b2f(q1.z), a1z); a1w = fmaf(w1, b2f(q1.w), a1w);
    a2x = fmaf(w2, b2f(q2.x), a2x); a2y = fmaf(w2, b2f(q2.y), a2y);
    a2z = fmaf(w2, b2f(q2.z), a2z); a2w = fmaf(w2, b2f(q2.w), a2w);
    a3x = fmaf(w3, b2f(q3.x), a3x); a3y = fmaf(w3, b2f(q3.y), a3y);
    a3z = fmaf(w3, b2f(q3.z), a3z); a3w = fmaf(w3, b2f(q3.w), a3w);
    d0 += w0; d1 += w1; d2 += w2; d3 += w3;
  }
  for (; i < c; ++i) {
    int s = eSrc[beg + i];
    float ev = as_[s * 4 + h] + adn;
    ev = fmaxf(ev, 0.2f * ev);
    w = __expf(ev);
    q = *(const ushort4*)(G16 + (size_t)s * 256 + lane * 4);
    a0x = fmaf(w, b2f(q.x), a0x); a0y = fmaf(w, b2f(q.y), a0y);
    a0z = fmaf(w, b2f(q.z), a0z); a0w = fmaf(w, b2f(q.w), a0w);
    d0 += w;
  }
  float ax = (a0x + a1x) + (a2x + a3x);
  float ay = (a0y + a1y) + (a2y + a3y);
  float az = (a0z + a1z) + (a2z + a3z);
  float aw = (a0w + a1w) + (a2w + a3w);
  float den = (d0 + d1) + (d2 + d3);

  float inv = 1.f / den;
  ax *= inv; ay *= inv; az *= inv; aw *= inv;

  // head-mean over lane bits 4,5
#pragma unroll
  for (int m = 32; m >= 16; m >>= 1) {
    ax += __shfl_xor(ax, m); ay += __shfl_xor(ay, m);
    az += __shfl_xor(az, m); aw += __shfl_xor(aw, m);
  }
  int fb = (lane & 15) * 4;
  float v0 = ax * 0.25f + bg[fb];
  float v1 = ay * 0.25f + bg[fb + 1];
  float v2 = az * 0.25f + bg[fb + 2];
  float v3 = aw * 0.25f + bg[fb + 3];

  float s1 = v0 + v1 + v2 + v3;
  float s2 = v0 * v0 + v1 * v1 + v2 * v2 + v3 * v3;
#pragma unroll
  for (int m = 8; m >= 1; m >>= 1) { s1 += __shfl_xor(s1, m); s2 += __shfl_xor(s2, m); }
  float mean = s1 * (1.f / 64.f);
  float var = s2 * (1.f / 64.f) - mean * mean;
  float rstd = rsqrtf(var + EPSV);
  if ((lane >> 4) == 0) {
    float4 o;
    o.x = (v0 - mean) * rstd * g3[fb] + be3[fb];
    o.y = (v1 - mean) * rstd * g3[fb + 1] + be3[fb + 1];
    o.z = (v2 - mean) * rstd * g3[fb + 2] + be3[fb + 2];
    o.w = (v3 - mean) * rstd * g3[fb + 3] + be3[fb + 3];
    *(float4*)(out + (size_t)n * 64 + fb) = o;
  }
}

// ================================================================ launch
extern "C" void kernel_launch(void* const* d_in, const int* in_sizes, int n_in,
                              void* d_out, int out_size, void* d_ws, size_t ws_size,
                              hipStream_t stream) {
  const float* x    = (const float*)d_in[0];
  const int*   edge = (const int*)d_in[1];
  const float* W_in = (const float*)d_in[2];
  const float* b_in = (const float*)d_in[3];
  const float* W1_l = (const float*)d_in[4];
  const float* b1   = (const float*)d_in[5];
  const float* W1_r = (const float*)d_in[6];
  const float* g1   = (const float*)d_in[7];
  const float* be1  = (const float*)d_in[8];
  const float* W2_l = (const float*)d_in[9];
  const float* b2   = (const float*)d_in[10];
  const float* W2_r = (const float*)d_in[11];
  const float* g2   = (const float*)d_in[12];
  const float* be2  = (const float*)d_in[13];
  const float* W_g  = (const float*)d_in[14];
  const float* atts = (const float*)d_in[15];
  const float* attd = (const float*)d_in[16];
  const float* b_g  = (const float*)d_in[17];
  const float* g3   = (const float*)d_in[18];
  const float* be3  = (const float*)d_in[19];

  const int nN = in_sizes[0] / 14;
  const int E_ = in_sizes[1] / 2;
  const int* src = edge;
  const int* dst = edge + E_;

  char* W = (char*)d_ws;
  unsigned short* hA16  = (unsigned short*)W; W += (size_t)nN * 128 * 2;
  unsigned short* hB16  = (unsigned short*)W; W += (size_t)nN * 128 * 2;
  unsigned short* agg16 = (unsigned short*)W; W += (size_t)nN * 128 * 2;
  unsigned short* G16   = (unsigned short*)W; W += (size_t)nN * 256 * 2;
  unsigned short* WlT   = (unsigned short*)W; W += 16384 * 2;
  unsigned short* WrT   = (unsigned short*)W; W += 16384 * 2;
  unsigned short* WgT   = (unsigned short*)W; W += 32768 * 2;
  float* AS_ = (float*)W;                W += (size_t)nN * 4 * 4;
  float* AD_ = (float*)W;                W += (size_t)nN * 4 * 4;
  int* cntI   = (int*)W;                 W += (size_t)nN * 4;
  int* rowptr = (int*)W;                 W += (size_t)nN * 4;
  int* cursor = (int*)W;                 W += (size_t)nN * 4;
  int* incl   = (int*)W;                 W += (size_t)nN * 4;
  int* bsum   = (int*)W;                 W += 1024 * 4;
  int* eSrc   = (int*)W;

  const int SB = (nN + 255) / 256;  // 196 for N=50000 (must be <=256)
  const int NB = (nN + 63) / 64;

  hipMemsetAsync(cntI, 0, (size_t)nN * sizeof(int), stream);
  hipMemsetAsync(cursor, 0, (size_t)nN * sizeof(int), stream);

  // CSR by dst
  k_count_int<<<(E_ + 255) / 256, 256, 0, stream>>>(dst, cntI, E_);
  k_scan1<<<SB, 256, 0, stream>>>(cntI, incl, bsum, nN);
  k_scan2<<<1, 256, 0, stream>>>(bsum, SB);
  k_scan3<<<SB, 256, 0, stream>>>(incl, bsum, cntI, rowptr, nN);
  k_fill<<<(E_ + 255) / 256, 256, 0, stream>>>(src, dst, rowptr, cursor, eSrc, E_);

  // weight prep + input projection
  k_prep3<<<256, 256, 0, stream>>>(W1_l, W1_r, W_g, WlT, WrT, WgT);
  k_proj<<<(nN * 128 + 255) / 256, 256, 0, stream>>>(x, W_in, b_in, hA16, nN);

  // SAGE layer 1: hA16 -> hB16
  k_sage_gather16<<<(nN * 32 + 255) / 256, 256, 0, stream>>>(hA16, rowptr, cntI, eSrc, agg16, nN);
  k_sage_mfma<<<NB, 256, 0, stream>>>(agg16, hA16, WlT, WrT, b1, g1, be1, hB16, nN);

  // SAGE layer 2: hB16 -> hA16   (re-prep: WlT/WrT now layer-2 weights)
  k_prep2<<<128, 256, 0, stream>>>(W2_l, W2_r, WlT, WrT);
  k_sage_gather16<<<(nN * 32 + 255) / 256, 256, 0, stream>>>(hB16, rowptr, cntI, eSrc, agg16, nN);
  k_sage_mfma<<<NB, 256, 0, stream>>>(agg16, hB16, WlT, WrT, b2, g2, be2, hA16, nN);

  // GAT: hA16 -> G16 (+logits) -> out
  k_gatgemm<<<dim3(NB, 2), 256, 0, stream>>>(hA16, WgT, atts, attd, G16, AS_, AD_, nN);
  k_gat<<<(nN * 64 + 255) / 256, 256, 0, stream>>>(G16, rowptr, cntI, eSrc, AS_, AD_, b_g, g3, be3, (float*)d_out, nN);
}

// Round 7
// 267.738 us; speedup vs baseline: 16.4913x; 1.0041x over previous
//
#include <hip/hip_runtime.h>
#include <math.h>

#define EPSV 1e-5f

typedef __attribute__((ext_vector_type(8))) short short8;
typedef __attribute__((ext_vector_type(4))) float f32x4;

__device__ __forceinline__ unsigned short f2b(float f) {
  union { float f; unsigned int u; } c; c.f = f;
  unsigned int u = c.u + 0x7fffu + ((c.u >> 16) & 1u);
  return (unsigned short)(u >> 16);
}
__device__ __forceinline__ float b2f(unsigned short h) {
  union { unsigned int u; float f; } c; c.u = ((unsigned int)h) << 16;
  return c.f;
}

// ---------------------------------------------------------------- weight prep
// layer1: WlT/WrT (128x128 each) + WgT (256x128)
__global__ void k_prep3(const float* __restrict__ Wl, const float* __restrict__ Wr,
                        const float* __restrict__ Wg, unsigned short* __restrict__ WlT,
                        unsigned short* __restrict__ WrT, unsigned short* __restrict__ WgT) {
  int id = blockIdx.x * 256 + threadIdx.x;  // 0..65535
  if (id < 16384) {
    int n = id >> 7, k = id & 127;
    WlT[id] = f2b(Wl[k * 128 + n]);
  } else if (id < 32768) {
    int j = id - 16384; int n = j >> 7, k = j & 127;
    WrT[j] = f2b(Wr[k * 128 + n]);
  } else {
    int j = id - 32768; int n = j >> 7, k = j & 127;
    WgT[j] = f2b(Wg[k * 256 + n]);
  }
}
// layer2: only Wl/Wr
__global__ void k_prep2(const float* __restrict__ Wl, const float* __restrict__ Wr,
                        unsigned short* __restrict__ WlT, unsigned short* __restrict__ WrT) {
  int id = blockIdx.x * 256 + threadIdx.x;  // 0..32767
  if (id < 16384) {
    int n = id >> 7, k = id & 127;
    WlT[id] = f2b(Wl[k * 128 + n]);
  } else {
    int j = id - 16384; int n = j >> 7, k = j & 127;
    WrT[j] = f2b(Wr[k * 128 + n]);
  }
}

// ---------------------------------------------------------------- input proj (bf16 out only)
__global__ void k_proj(const float* __restrict__ x, const float* __restrict__ W,
                       const float* __restrict__ b, unsigned short* __restrict__ h16, int nN) {
  int gid = blockIdx.x * 256 + threadIdx.x;
  if (gid >= nN * 128) return;
  int n = gid >> 7, f = gid & 127;
  const float* xr = x + n * 14;
  float acc = b[f];
#pragma unroll
  for (int k = 0; k < 14; ++k) acc = fmaf(xr[k], W[k * 128 + f], acc);
  h16[gid] = f2b(fmaxf(acc, 0.f));
}

// ---------------------------------------------------------------- degree count
__global__ void k_count_int(const int* __restrict__ dst, int* __restrict__ cnt, int E_) {
  int e = blockIdx.x * 256 + threadIdx.x;
  if (e < E_) atomicAdd(&cnt[dst[e]], 1);
}

// ---------------------------------------------------------------- scan (3-phase)
__global__ void k_scan1(const int* __restrict__ cnt, int* __restrict__ incl,
                        int* __restrict__ bsum, int nN) {
  __shared__ int sh[256];
  int tid = threadIdx.x;
  int i = blockIdx.x * 256 + tid;
  int v = (i < nN) ? cnt[i] : 0;
  sh[tid] = v;
  __syncthreads();
#pragma unroll
  for (int off = 1; off < 256; off <<= 1) {
    int t = (tid >= off) ? sh[tid - off] : 0;
    __syncthreads();
    sh[tid] += t;
    __syncthreads();
  }
  if (i < nN) incl[i] = sh[tid];
  if (tid == 255) bsum[blockIdx.x] = sh[255];
}

__global__ void k_scan2(int* __restrict__ bsum, int nb) {
  __shared__ int sh[256];
  int tid = threadIdx.x;
  int v = (tid < nb) ? bsum[tid] : 0;
  sh[tid] = v;
  __syncthreads();
#pragma unroll
  for (int off = 1; off < 256; off <<= 1) {
    int t = (tid >= off) ? sh[tid - off] : 0;
    __syncthreads();
    sh[tid] += t;
    __syncthreads();
  }
  if (tid < nb) bsum[tid] = sh[tid] - v;  // exclusive
}

__global__ void k_scan3(const int* __restrict__ incl, const int* __restrict__ bsum,
                        const int* __restrict__ cnt, int* __restrict__ rowptr, int nN) {
  int i = blockIdx.x * 256 + threadIdx.x;
  if (i < nN) rowptr[i] = incl[i] - cnt[i] + bsum[blockIdx.x];
}

// ---------------------------------------------------------------- CSR fill
__global__ void k_fill(const int* __restrict__ src, const int* __restrict__ dst,
                       const int* __restrict__ rowptr, int* __restrict__ cursor,
                       int* __restrict__ eSrc, int E_) {
  int e = blockIdx.x * 256 + threadIdx.x;
  if (e >= E_) return;
  int d = dst[e];
  int pos = rowptr[d] + atomicAdd(&cursor[d], 1);
  eSrc[pos] = src[e];
}

// ---------------------------------------------------------------- SAGE gather-mean
// 16 lanes/node, 8 feats/lane (ushort8 = 16B); 4 accumulator banks
__global__ void k_sage_gather16(const unsigned short* __restrict__ h16,
                                const int* __restrict__ rowptr, const int* __restrict__ cnt,
                                const int* __restrict__ eSrc,
                                unsigned short* __restrict__ agg16, int nN) {
  int t = blockIdx.x * 256 + threadIdx.x;
  int n = t >> 4;
  if (n >= nN) return;
  int sub = t & 15;
  int fo = sub * 8;
  int beg = rowptr[n], c = cnt[n];
  float a0[8], a1[8], a2[8], a3[8];
#pragma unroll
  for (int j = 0; j < 8; ++j) { a0[j] = 0.f; a1[j] = 0.f; a2[j] = 0.f; a3[j] = 0.f; }
  int i = 0;
  for (; i + 4 <= c; i += 4) {
    int s0 = eSrc[beg + i], s1 = eSrc[beg + i + 1];
    int s2 = eSrc[beg + i + 2], s3 = eSrc[beg + i + 3];
    short8 q0 = *(const short8*)(h16 + (size_t)s0 * 128 + fo);
    short8 q1 = *(const short8*)(h16 + (size_t)s1 * 128 + fo);
    short8 q2 = *(const short8*)(h16 + (size_t)s2 * 128 + fo);
    short8 q3 = *(const short8*)(h16 + (size_t)s3 * 128 + fo);
#pragma unroll
    for (int j = 0; j < 8; ++j) {
      a0[j] += b2f((unsigned short)q0[j]);
      a1[j] += b2f((unsigned short)q1[j]);
      a2[j] += b2f((unsigned short)q2[j]);
      a3[j] += b2f((unsigned short)q3[j]);
    }
  }
  for (; i < c; ++i) {
    int s = eSrc[beg + i];
    short8 q = *(const short8*)(h16 + (size_t)s * 128 + fo);
#pragma unroll
    for (int j = 0; j < 8; ++j) a0[j] += b2f((unsigned short)q[j]);
  }
  float inv = 1.f / fmaxf((float)c, 1.f);
  short8 r;
#pragma unroll
  for (int j = 0; j < 8; ++j)
    r[j] = (short)f2b(((a0[j] + a1[j]) + (a2[j] + a3[j])) * inv);
  *(short8*)(agg16 + (size_t)n * 128 + fo) = r;
}

// ---------------------------------------------------------------- SAGE MFMA layer
// Hout16 = bf16( relu(LN([agg|Hin] @ [Wl;Wr] + bias)) + Hin )
__global__ __launch_bounds__(256)
void k_sage_mfma(const unsigned short* __restrict__ agg16,
                 const unsigned short* __restrict__ hin16,
                 const unsigned short* __restrict__ WlT,
                 const unsigned short* __restrict__ WrT,
                 const float* __restrict__ bias, const float* __restrict__ gam,
                 const float* __restrict__ bet,
                 unsigned short* __restrict__ hout16, int nN) {
  __shared__ unsigned short lA[64][136];
  __shared__ unsigned short lB[128][136];
  int tid = threadIdx.x;
  int wave = tid >> 6, lane = tid & 63;
  int cl = lane & 15, g = lane >> 4;
  int rowBase = blockIdx.x * 64;
  f32x4 acc[8];
#pragma unroll
  for (int ct = 0; ct < 8; ++ct) acc[ct] = (f32x4){0.f, 0.f, 0.f, 0.f};

  int ar = tid >> 2, ap = (tid & 3) * 32;  // A stage: row, k-part
  int br = tid >> 1, bp = (tid & 1) * 64;  // B stage: row, k-part

  for (int half = 0; half < 2; ++half) {
    const unsigned short* At = half ? hin16 : agg16;
    const unsigned short* Bt = half ? WrT : WlT;
    if (half) __syncthreads();
    {
      int grow = rowBase + ar;
      if (grow < nN) {
        const unsigned short* sp = At + (size_t)grow * 128 + ap;
#pragma unroll
        for (int u = 0; u < 4; ++u)
          *(short8*)&lA[ar][ap + u * 8] = *(const short8*)(sp + u * 8);
      } else {
        short8 z = {0, 0, 0, 0, 0, 0, 0, 0};
#pragma unroll
        for (int u = 0; u < 4; ++u) *(short8*)&lA[ar][ap + u * 8] = z;
      }
      const unsigned short* bsp = Bt + (size_t)br * 128 + bp;
#pragma unroll
      for (int u = 0; u < 8; ++u)
        *(short8*)&lB[br][bp + u * 8] = *(const short8*)(bsp + u * 8);
    }
    __syncthreads();
#pragma unroll
    for (int ks = 0; ks < 4; ++ks) {
      short8 a = *(const short8*)&lA[wave * 16 + cl][ks * 32 + g * 8];
#pragma unroll
      for (int ct = 0; ct < 8; ++ct) {
        short8 b = *(const short8*)&lB[ct * 16 + cl][ks * 32 + g * 8];
        acc[ct] = __builtin_amdgcn_mfma_f32_16x16x32_bf16(a, b, acc[ct], 0, 0, 0);
      }
    }
  }
  __syncthreads();

  // epilogue: +bias, LN over 128 cols, *gam+bet, relu, +residual(bf16)
  float bcol[8], gcol[8], ecol[8];
#pragma unroll
  for (int ct = 0; ct < 8; ++ct) {
    int c = ct * 16 + cl;
    bcol[ct] = bias[c]; gcol[ct] = gam[c]; ecol[ct] = bet[c];
  }
  float v[8][4];
  float s1[4] = {0.f, 0.f, 0.f, 0.f}, s2[4] = {0.f, 0.f, 0.f, 0.f};
#pragma unroll
  for (int ct = 0; ct < 8; ++ct)
#pragma unroll
    for (int r = 0; r < 4; ++r) {
      float t = acc[ct][r] + bcol[ct];
      v[ct][r] = t;
      s1[r] += t; s2[r] += t * t;
    }
#pragma unroll
  for (int m = 1; m <= 8; m <<= 1)
#pragma unroll
    for (int r = 0; r < 4; ++r) { s1[r] += __shfl_xor(s1[r], m); s2[r] += __shfl_xor(s2[r], m); }

#pragma unroll
  for (int r = 0; r < 4; ++r) {
    float mean = s1[r] * (1.f / 128.f);
    float var = s2[r] * (1.f / 128.f) - mean * mean;
    float rstd = rsqrtf(var + EPSV);
    int grow = rowBase + wave * 16 + g * 4 + r;
    if (grow < nN) {
#pragma unroll
      for (int ct = 0; ct < 8; ++ct) {
        int c = ct * 16 + cl;
        float o = fmaxf((v[ct][r] - mean) * rstd * gcol[ct] + ecol[ct], 0.f)
                  + b2f(hin16[(size_t)grow * 128 + c]);
        hout16[(size_t)grow * 128 + c] = f2b(o);
      }
    }
  }
}

// ---------------------------------------------------------------- GAT GEMM (MFMA) + logits
// G[:,y*128..y*128+127] = h @ Wg[:, half y]; logits for heads 2y, 2y+1
__global__ __launch_bounds__(256)
void k_gatgemm(const unsigned short* __restrict__ h16, const unsigned short* __restrict__ WgT,
               const float* __restrict__ atts, const float* __restrict__ attd,
               unsigned short* __restrict__ G16, float* __restrict__ as_,
               float* __restrict__ ad_, int nN) {
  __shared__ unsigned short lA[64][136];
  __shared__ unsigned short lB[128][136];
  int tid = threadIdx.x;
  int wave = tid >> 6, lane = tid & 63;
  int cl = lane & 15, g = lane >> 4;
  int rowBase = blockIdx.x * 64;
  int y = blockIdx.y;
  f32x4 acc[8];
#pragma unroll
  for (int ct = 0; ct < 8; ++ct) acc[ct] = (f32x4){0.f, 0.f, 0.f, 0.f};

  int ar = tid >> 2, ap = (tid & 3) * 32;
  int br = tid >> 1, bp = (tid & 1) * 64;
  {
    int grow = rowBase + ar;
    if (grow < nN) {
      const unsigned short* sp = h16 + (size_t)grow * 128 + ap;
#pragma unroll
      for (int u = 0; u < 4; ++u)
        *(short8*)&lA[ar][ap + u * 8] = *(const short8*)(sp + u * 8);
    } else {
      short8 z = {0, 0, 0, 0, 0, 0, 0, 0};
#pragma unroll
      for (int u = 0; u < 4; ++u) *(short8*)&lA[ar][ap + u * 8] = z;
    }
    const unsigned short* bsp = WgT + (size_t)(y * 128 + br) * 128 + bp;
#pragma unroll
    for (int u = 0; u < 8; ++u)
      *(short8*)&lB[br][bp + u * 8] = *(const short8*)(bsp + u * 8);
  }
  __syncthreads();
#pragma unroll
  for (int ks = 0; ks < 4; ++ks) {
    short8 a = *(const short8*)&lA[wave * 16 + cl][ks * 32 + g * 8];
#pragma unroll
    for (int ct = 0; ct < 8; ++ct) {
      short8 b = *(const short8*)&lB[ct * 16 + cl][ks * 32 + g * 8];
      acc[ct] = __builtin_amdgcn_mfma_f32_16x16x32_bf16(a, b, acc[ct], 0, 0, 0);
    }
  }

  // epilogue: store G16 + attention logits for heads 2y+hh (hh = ct>>2)
  float atr[8], adr[8];
#pragma unroll
  for (int ct = 0; ct < 8; ++ct) {
    int h = y * 2 + (ct >> 2);
    int w = (ct & 3) * 16 + cl;  // col within head
    atr[ct] = atts[h * 64 + w];
    adr[ct] = attd[h * 64 + w];
  }
  float ps[2][4], pd[2][4];
#pragma unroll
  for (int hh = 0; hh < 2; ++hh)
#pragma unroll
    for (int r = 0; r < 4; ++r) { ps[hh][r] = 0.f; pd[hh][r] = 0.f; }

#pragma unroll
  for (int r = 0; r < 4; ++r) {
    int grow = rowBase + wave * 16 + g * 4 + r;
    if (grow < nN) {
      unsigned short* op = G16 + (size_t)grow * 256 + y * 128 + cl;
#pragma unroll
      for (int ct = 0; ct < 8; ++ct) op[ct * 16] = f2b(acc[ct][r]);
    }
#pragma unroll
    for (int ct = 0; ct < 8; ++ct) {
      ps[ct >> 2][r] = fmaf(acc[ct][r], atr[ct], ps[ct >> 2][r]);
      pd[ct >> 2][r] = fmaf(acc[ct][r], adr[ct], pd[ct >> 2][r]);
    }
  }
#pragma unroll
  for (int m = 1; m <= 8; m <<= 1)
#pragma unroll
    for (int hh = 0; hh < 2; ++hh)
#pragma unroll
      for (int r = 0; r < 4; ++r) {
        ps[hh][r] += __shfl_xor(ps[hh][r], m);
        pd[hh][r] += __shfl_xor(pd[hh][r], m);
      }
  if (cl == 0) {
#pragma unroll
    for (int r = 0; r < 4; ++r) {
      int grow = rowBase + wave * 16 + g * 4 + r;
      if (grow < nN) {
#pragma unroll
        for (int hh = 0; hh < 2; ++hh) {
          as_[grow * 4 + y * 2 + hh] = ps[hh][r];
          ad_[grow * 4 + y * 2 + hh] = pd[hh][r];
        }
      }
    }
  }
}

// ---------------------------------------------------------------- fused GAT gather + LN
// 32 lanes/node, 8 feats/lane (ushort8); head = sub>>3; unroll x4;
// leaky=max(x,0.2x); native exp
__global__ void k_gat(const unsigned short* __restrict__ G16, const int* __restrict__ rowptr,
                      const int* __restrict__ cnt, const int* __restrict__ eSrc,
                      const float* __restrict__ as_, const float* __restrict__ ad_,
                      const float* __restrict__ bg, const float* __restrict__ g3,
                      const float* __restrict__ be3, float* __restrict__ out, int nN) {
  int t = blockIdx.x * 256 + threadIdx.x;
  int n = t >> 5;
  if (n >= nN) return;
  int sub = t & 31;
  int h = sub >> 3;
  int fo = sub * 8;  // global col base in [0,256)
  float adn = ad_[n * 4 + h];

  // self loop -> bank 0
  float e0 = as_[n * 4 + h] + adn;
  e0 = fmaxf(e0, 0.2f * e0);
  float w = __expf(e0);
  short8 q = *(const short8*)(G16 + (size_t)n * 256 + fo);
  float a0[8], a1[8], a2[8], a3[8];
#pragma unroll
  for (int j = 0; j < 8; ++j) {
    a0[j] = w * b2f((unsigned short)q[j]);
    a1[j] = 0.f; a2[j] = 0.f; a3[j] = 0.f;
  }
  float d0 = w, d1 = 0.f, d2 = 0.f, d3 = 0.f;

  int beg = rowptr[n], c = cnt[n];
  int i = 0;
  for (; i + 4 <= c; i += 4) {
    int s0 = eSrc[beg + i], s1i = eSrc[beg + i + 1];
    int s2i = eSrc[beg + i + 2], s3i = eSrc[beg + i + 3];
    float ev0 = as_[s0 * 4 + h] + adn;
    float ev1 = as_[s1i * 4 + h] + adn;
    float ev2 = as_[s2i * 4 + h] + adn;
    float ev3 = as_[s3i * 4 + h] + adn;
    ev0 = fmaxf(ev0, 0.2f * ev0); ev1 = fmaxf(ev1, 0.2f * ev1);
    ev2 = fmaxf(ev2, 0.2f * ev2); ev3 = fmaxf(ev3, 0.2f * ev3);
    float w0 = __expf(ev0), w1 = __expf(ev1), w2 = __expf(ev2), w3 = __expf(ev3);
    short8 q0 = *(const short8*)(G16 + (size_t)s0 * 256 + fo);
    short8 q1 = *(const short8*)(G16 + (size_t)s1i * 256 + fo);
    short8 q2 = *(const short8*)(G16 + (size_t)s2i * 256 + fo);
    short8 q3 = *(const short8*)(G16 + (size_t)s3i * 256 + fo);
#pragma unroll
    for (int j = 0; j < 8; ++j) {
      a0[j] = fmaf(w0, b2f((unsigned short)q0[j]), a0[j]);
      a1[j] = fmaf(w1, b2f((unsigned short)q1[j]), a1[j]);
      a2[j] = fmaf(w2, b2f((unsigned short)q2[j]), a2[j]);
      a3[j] = fmaf(w3, b2f((unsigned short)q3[j]), a3[j]);
    }
    d0 += w0; d1 += w1; d2 += w2; d3 += w3;
  }
  for (; i < c; ++i) {
    int s = eSrc[beg + i];
    float ev = as_[s * 4 + h] + adn;
    ev = fmaxf(ev, 0.2f * ev);
    w = __expf(ev);
    q = *(const short8*)(G16 + (size_t)s * 256 + fo);
#pragma unroll
    for (int j = 0; j < 8; ++j) a0[j] = fmaf(w, b2f((unsigned short)q[j]), a0[j]);
    d0 += w;
  }

  float den = (d0 + d1) + (d2 + d3);
  float inv = 1.f / den;
  float a[8];
#pragma unroll
  for (int j = 0; j < 8; ++j) a[j] = ((a0[j] + a1[j]) + (a2[j] + a3[j])) * inv;

  // head-mean: sum over lane bits 3,4 (head index); lanes with equal sub&7
  // then hold identical values for feats (sub&7)*8..+7
#pragma unroll
  for (int j = 0; j < 8; ++j) {
    a[j] += __shfl_xor(a[j], 8);
    a[j] += __shfl_xor(a[j], 16);
  }
  int fb = (sub & 7) * 8;  // output feat base in [0,64)
  float v[8];
  float s1 = 0.f, s2 = 0.f;
#pragma unroll
  for (int j = 0; j < 8; ++j) {
    v[j] = a[j] * 0.25f + bg[fb + j];
    s1 += v[j]; s2 += v[j] * v[j];
  }
  // LN over 64 feats: reduce across lane bits 0-2
#pragma unroll
  for (int m = 1; m <= 4; m <<= 1) { s1 += __shfl_xor(s1, m); s2 += __shfl_xor(s2, m); }
  float mean = s1 * (1.f / 64.f);
  float var = s2 * (1.f / 64.f) - mean * mean;
  float rstd = rsqrtf(var + EPSV);
  if (sub < 8) {
    float* o = out + (size_t)n * 64 + fb;
    float4 o1, o2;
    o1.x = (v[0] - mean) * rstd * g3[fb + 0] + be3[fb + 0];
    o1.y = (v[1] - mean) * rstd * g3[fb + 1] + be3[fb + 1];
    o1.z = (v[2] - mean) * rstd * g3[fb + 2] + be3[fb + 2];
    o1.w = (v[3] - mean) * rstd * g3[fb + 3] + be3[fb + 3];
    o2.x = (v[4] - mean) * rstd * g3[fb + 4] + be3[fb + 4];
    o2.y = (v[5] - mean) * rstd * g3[fb + 5] + be3[fb + 5];
    o2.z = (v[6] - mean) * rstd * g3[fb + 6] + be3[fb + 6];
    o2.w = (v[7] - mean) * rstd * g3[fb + 7] + be3[fb + 7];
    *(float4*)o = o1;
    *(float4*)(o + 4) = o2;
  }
}

// ================================================================ launch
extern "C" void kernel_launch(void* const* d_in, const int* in_sizes, int n_in,
                              void* d_out, int out_size, void* d_ws, size_t ws_size,
                              hipStream_t stream) {
  const float* x    = (const float*)d_in[0];
  const int*   edge = (const int*)d_in[1];
  const float* W_in = (const float*)d_in[2];
  const float* b_in = (const float*)d_in[3];
  const float* W1_l = (const float*)d_in[4];
  const float* b1   = (const float*)d_in[5];
  const float* W1_r = (const float*)d_in[6];
  const float* g1   = (const float*)d_in[7];
  const float* be1  = (const float*)d_in[8];
  const float* W2_l = (const float*)d_in[9];
  const float* b2   = (const float*)d_in[10];
  const float* W2_r = (const float*)d_in[11];
  const float* g2   = (const float*)d_in[12];
  const float* be2  = (const float*)d_in[13];
  const float* W_g  = (const float*)d_in[14];
  const float* atts = (const float*)d_in[15];
  const float* attd = (const float*)d_in[16];
  const float* b_g  = (const float*)d_in[17];
  const float* g3   = (const float*)d_in[18];
  const float* be3  = (const float*)d_in[19];

  const int nN = in_sizes[0] / 14;
  const int E_ = in_sizes[1] / 2;
  const int* src = edge;
  const int* dst = edge + E_;

  char* W = (char*)d_ws;
  unsigned short* hA16  = (unsigned short*)W; W += (size_t)nN * 128 * 2;
  unsigned short* hB16  = (unsigned short*)W; W += (size_t)nN * 128 * 2;
  unsigned short* agg16 = (unsigned short*)W; W += (size_t)nN * 128 * 2;
  unsigned short* G16   = (unsigned short*)W; W += (size_t)nN * 256 * 2;
  unsigned short* WlT   = (unsigned short*)W; W += 16384 * 2;
  unsigned short* WrT   = (unsigned short*)W; W += 16384 * 2;
  unsigned short* WgT   = (unsigned short*)W; W += 32768 * 2;
  float* AS_ = (float*)W;                W += (size_t)nN * 4 * 4;
  float* AD_ = (float*)W;                W += (size_t)nN * 4 * 4;
  int* cntI   = (int*)W;                 W += (size_t)nN * 4;
  int* rowptr = (int*)W;                 W += (size_t)nN * 4;
  int* cursor = (int*)W;                 W += (size_t)nN * 4;
  int* incl   = (int*)W;                 W += (size_t)nN * 4;
  int* bsum   = (int*)W;                 W += 1024 * 4;
  int* eSrc   = (int*)W;

  const int SB = (nN + 255) / 256;  // 196 for N=50000 (must be <=256)
  const int NB = (nN + 63) / 64;

  hipMemsetAsync(cntI, 0, (size_t)nN * sizeof(int), stream);
  hipMemsetAsync(cursor, 0, (size_t)nN * sizeof(int), stream);

  // CSR by dst
  k_count_int<<<(E_ + 255) / 256, 256, 0, stream>>>(dst, cntI, E_);
  k_scan1<<<SB, 256, 0, stream>>>(cntI, incl, bsum, nN);
  k_scan2<<<1, 256, 0, stream>>>(bsum, SB);
  k_scan3<<<SB, 256, 0, stream>>>(incl, bsum, cntI, rowptr, nN);
  k_fill<<<(E_ + 255) / 256, 256, 0, stream>>>(src, dst, rowptr, cursor, eSrc, E_);

  // weight prep + input projection
  k_prep3<<<256, 256, 0, stream>>>(W1_l, W1_r, W_g, WlT, WrT, WgT);
  k_proj<<<(nN * 128 + 255) / 256, 256, 0, stream>>>(x, W_in, b_in, hA16, nN);

  // SAGE layer 1: hA16 -> hB16
  k_sage_gather16<<<(nN * 16 + 255) / 256, 256, 0, stream>>>(hA16, rowptr, cntI, eSrc, agg16, nN);
  k_sage_mfma<<<NB, 256, 0, stream>>>(agg16, hA16, WlT, WrT, b1, g1, be1, hB16, nN);

  // SAGE layer 2: hB16 -> hA16   (re-prep: WlT/WrT now layer-2 weights)
  k_prep2<<<128, 256, 0, stream>>>(W2_l, W2_r, WlT, WrT);
  k_sage_gather16<<<(nN * 16 + 255) / 256, 256, 0, stream>>>(hB16, rowptr, cntI, eSrc, agg16, nN);
  k_sage_mfma<<<NB, 256, 0, stream>>>(agg16, hB16, WlT, WrT, b2, g2, be2, hA16, nN);

  // GAT: hA16 -> G16 (+logits) -> out
  k_gatgemm<<<dim3(NB, 2), 256, 0, stream>>>(hA16, WgT, atts, attd, G16, AS_, AD_, nN);
  k_gat<<<(nN * 32 + 255) / 256, 256, 0, stream>>>(G16, rowptr, cntI, eSrc, AS_, AD_, b_g, g3, be3, (float*)d_out, nN);
}

// Round 8
// 265.533 us; speedup vs baseline: 16.6282x; 1.0083x over previous
//
#include <hip/hip_runtime.h>
#include <math.h>

#define EPSV 1e-5f

typedef __attribute__((ext_vector_type(8))) short short8;
typedef __attribute__((ext_vector_type(4))) float f32x4;

__device__ __forceinline__ unsigned short f2b(float f) {
  union { float f; unsigned int u; } c; c.f = f;
  unsigned int u = c.u + 0x7fffu + ((c.u >> 16) & 1u);
  return (unsigned short)(u >> 16);
}
__device__ __forceinline__ float b2f(unsigned short h) {
  union { unsigned int u; float f; } c; c.u = ((unsigned int)h) << 16;
  return c.f;
}
__device__ __forceinline__ float ub(unsigned int w, int j) {  // byte j of dword -> float
  return (float)((w >> (8 * j)) & 0xffu);
}

// ---------------------------------------------------------------- weight prep
__global__ void k_prep3(const float* __restrict__ Wl, const float* __restrict__ Wr,
                        const float* __restrict__ Wg, unsigned short* __restrict__ WlT,
                        unsigned short* __restrict__ WrT, unsigned short* __restrict__ WgT) {
  int id = blockIdx.x * 256 + threadIdx.x;  // 0..65535
  if (id < 16384) {
    int n = id >> 7, k = id & 127;
    WlT[id] = f2b(Wl[k * 128 + n]);
  } else if (id < 32768) {
    int j = id - 16384; int n = j >> 7, k = j & 127;
    WrT[j] = f2b(Wr[k * 128 + n]);
  } else {
    int j = id - 32768; int n = j >> 7, k = j & 127;
    WgT[j] = f2b(Wg[k * 256 + n]);
  }
}
__global__ void k_prep2(const float* __restrict__ Wl, const float* __restrict__ Wr,
                        unsigned short* __restrict__ WlT, unsigned short* __restrict__ WrT) {
  int id = blockIdx.x * 256 + threadIdx.x;  // 0..32767
  if (id < 16384) {
    int n = id >> 7, k = id & 127;
    WlT[id] = f2b(Wl[k * 128 + n]);
  } else {
    int j = id - 16384; int n = j >> 7, k = j & 127;
    WrT[j] = f2b(Wr[k * 128 + n]);
  }
}

// ---------------------------------------------------------------- input proj
// 64 lanes/node, 2 feats/lane; writes bf16 + uint8(rowquant) + meta
__global__ void k_proj(const float* __restrict__ x, const float* __restrict__ W,
                       const float* __restrict__ b, unsigned short* __restrict__ h16,
                       unsigned char* __restrict__ h8, float2* __restrict__ hmeta, int nN) {
  int t = blockIdx.x * 256 + threadIdx.x;
  int n = t >> 6;
  if (n >= nN) return;
  int lane = t & 63;
  const float* xr = x + (size_t)n * 14;
  float acc0 = b[lane], acc1 = b[lane + 64];
#pragma unroll
  for (int k = 0; k < 14; ++k) {
    float xv = xr[k];
    acc0 = fmaf(xv, W[k * 128 + lane], acc0);
    acc1 = fmaf(xv, W[k * 128 + lane + 64], acc1);
  }
  float o0 = fmaxf(acc0, 0.f), o1 = fmaxf(acc1, 0.f);
  h16[(size_t)n * 128 + lane] = f2b(o0);
  h16[(size_t)n * 128 + lane + 64] = f2b(o1);
  float rmin = fminf(o0, o1), rmax = fmaxf(o0, o1);
#pragma unroll
  for (int m = 1; m <= 32; m <<= 1) {
    rmin = fminf(rmin, __shfl_xor(rmin, m));
    rmax = fmaxf(rmax, __shfl_xor(rmax, m));
  }
  float scale = (rmax - rmin) * (1.f / 255.f);
  float invq = (rmax > rmin) ? 255.f / (rmax - rmin) : 0.f;
  h8[(size_t)n * 128 + lane] = (unsigned char)(int)rintf((o0 - rmin) * invq);
  h8[(size_t)n * 128 + lane + 64] = (unsigned char)(int)rintf((o1 - rmin) * invq);
  if (lane == 0) hmeta[n] = make_float2(scale, rmin);
}

// ---------------------------------------------------------------- degree count
__global__ void k_count_int(const int* __restrict__ dst, int* __restrict__ cnt, int E_) {
  int e = blockIdx.x * 256 + threadIdx.x;
  if (e < E_) atomicAdd(&cnt[dst[e]], 1);
}

// ---------------------------------------------------------------- scan (3-phase)
__global__ void k_scan1(const int* __restrict__ cnt, int* __restrict__ incl,
                        int* __restrict__ bsum, int nN) {
  __shared__ int sh[256];
  int tid = threadIdx.x;
  int i = blockIdx.x * 256 + tid;
  int v = (i < nN) ? cnt[i] : 0;
  sh[tid] = v;
  __syncthreads();
#pragma unroll
  for (int off = 1; off < 256; off <<= 1) {
    int t = (tid >= off) ? sh[tid - off] : 0;
    __syncthreads();
    sh[tid] += t;
    __syncthreads();
  }
  if (i < nN) incl[i] = sh[tid];
  if (tid == 255) bsum[blockIdx.x] = sh[255];
}

__global__ void k_scan2(int* __restrict__ bsum, int nb) {
  __shared__ int sh[256];
  int tid = threadIdx.x;
  int v = (tid < nb) ? bsum[tid] : 0;
  sh[tid] = v;
  __syncthreads();
#pragma unroll
  for (int off = 1; off < 256; off <<= 1) {
    int t = (tid >= off) ? sh[tid - off] : 0;
    __syncthreads();
    sh[tid] += t;
    __syncthreads();
  }
  if (tid < nb) bsum[tid] = sh[tid] - v;  // exclusive
}

__global__ void k_scan3(const int* __restrict__ incl, const int* __restrict__ bsum,
                        const int* __restrict__ cnt, int* __restrict__ rowptr, int nN) {
  int i = blockIdx.x * 256 + threadIdx.x;
  if (i < nN) rowptr[i] = incl[i] - cnt[i] + bsum[blockIdx.x];
}

// ---------------------------------------------------------------- CSR fill
__global__ void k_fill(const int* __restrict__ src, const int* __restrict__ dst,
                       const int* __restrict__ rowptr, int* __restrict__ cursor,
                       int* __restrict__ eSrc, int E_) {
  int e = blockIdx.x * 256 + threadIdx.x;
  if (e >= E_) return;
  int d = dst[e];
  int pos = rowptr[d] + atomicAdd(&cursor[d], 1);
  eSrc[pos] = src[e];
}

// ---------------------------------------------------------------- SAGE gather-mean (uint8)
// 16 lanes/node, 8 feats/lane (uchar8 = 8B); 4 banks; x = min + scale*q
__global__ void k_sage_gather8(const unsigned char* __restrict__ h8,
                               const float2* __restrict__ hmeta,
                               const int* __restrict__ rowptr, const int* __restrict__ cnt,
                               const int* __restrict__ eSrc,
                               unsigned short* __restrict__ agg16, int nN) {
  int t = blockIdx.x * 256 + threadIdx.x;
  int n = t >> 4;
  if (n >= nN) return;
  int sub = t & 15;
  int fo = sub * 8;
  int beg = rowptr[n], c = cnt[n];
  float a0[8], a1[8], a2[8], a3[8];
#pragma unroll
  for (int j = 0; j < 8; ++j) { a0[j] = 0.f; a1[j] = 0.f; a2[j] = 0.f; a3[j] = 0.f; }
  float m0 = 0.f, m1 = 0.f, m2 = 0.f, m3 = 0.f;
  int i = 0;
  for (; i + 4 <= c; i += 4) {
    int s0 = eSrc[beg + i], s1 = eSrc[beg + i + 1];
    int s2 = eSrc[beg + i + 2], s3 = eSrc[beg + i + 3];
    float2 t0 = hmeta[s0], t1 = hmeta[s1], t2 = hmeta[s2], t3 = hmeta[s3];
    uint2 p0 = *(const uint2*)(h8 + (size_t)s0 * 128 + fo);
    uint2 p1 = *(const uint2*)(h8 + (size_t)s1 * 128 + fo);
    uint2 p2 = *(const uint2*)(h8 + (size_t)s2 * 128 + fo);
    uint2 p3 = *(const uint2*)(h8 + (size_t)s3 * 128 + fo);
#pragma unroll
    for (int j = 0; j < 4; ++j) {
      a0[j] = fmaf(t0.x, ub(p0.x, j), a0[j]);
      a1[j] = fmaf(t1.x, ub(p1.x, j), a1[j]);
      a2[j] = fmaf(t2.x, ub(p2.x, j), a2[j]);
      a3[j] = fmaf(t3.x, ub(p3.x, j), a3[j]);
      a0[j + 4] = fmaf(t0.x, ub(p0.y, j), a0[j + 4]);
      a1[j + 4] = fmaf(t1.x, ub(p1.y, j), a1[j + 4]);
      a2[j + 4] = fmaf(t2.x, ub(p2.y, j), a2[j + 4]);
      a3[j + 4] = fmaf(t3.x, ub(p3.y, j), a3[j + 4]);
    }
    m0 += t0.y; m1 += t1.y; m2 += t2.y; m3 += t3.y;
  }
  for (; i < c; ++i) {
    int s = eSrc[beg + i];
    float2 tm = hmeta[s];
    uint2 p = *(const uint2*)(h8 + (size_t)s * 128 + fo);
#pragma unroll
    for (int j = 0; j < 4; ++j) {
      a0[j] = fmaf(tm.x, ub(p.x, j), a0[j]);
      a0[j + 4] = fmaf(tm.x, ub(p.y, j), a0[j + 4]);
    }
    m0 += tm.y;
  }
  float mm = (m0 + m1) + (m2 + m3);
  float inv = 1.f / fmaxf((float)c, 1.f);
  short8 r;
#pragma unroll
  for (int j = 0; j < 8; ++j)
    r[j] = (short)f2b((((a0[j] + a1[j]) + (a2[j] + a3[j])) + mm) * inv);
  *(short8*)(agg16 + (size_t)n * 128 + fo) = r;
}

// ---------------------------------------------------------------- SAGE MFMA layer
// Hout16 = bf16( relu(LN([agg|Hin] @ [Wl;Wr] + bias)) + Hin ); optional uint8 out
__global__ __launch_bounds__(256)
void k_sage_mfma(const unsigned short* __restrict__ agg16,
                 const unsigned short* __restrict__ hin16,
                 const unsigned short* __restrict__ WlT,
                 const unsigned short* __restrict__ WrT,
                 const float* __restrict__ bias, const float* __restrict__ gam,
                 const float* __restrict__ bet,
                 unsigned short* __restrict__ hout16,
                 unsigned char* __restrict__ hout8, float2* __restrict__ hmeta_o,
                 int quant, int nN) {
  __shared__ unsigned short lA[64][136];
  __shared__ unsigned short lB[128][136];
  int tid = threadIdx.x;
  int wave = tid >> 6, lane = tid & 63;
  int cl = lane & 15, g = lane >> 4;
  int rowBase = blockIdx.x * 64;
  f32x4 acc[8];
#pragma unroll
  for (int ct = 0; ct < 8; ++ct) acc[ct] = (f32x4){0.f, 0.f, 0.f, 0.f};

  int ar = tid >> 2, ap = (tid & 3) * 32;
  int br = tid >> 1, bp = (tid & 1) * 64;

  for (int half = 0; half < 2; ++half) {
    const unsigned short* At = half ? hin16 : agg16;
    const unsigned short* Bt = half ? WrT : WlT;
    if (half) __syncthreads();
    {
      int grow = rowBase + ar;
      if (grow < nN) {
        const unsigned short* sp = At + (size_t)grow * 128 + ap;
#pragma unroll
        for (int u = 0; u < 4; ++u)
          *(short8*)&lA[ar][ap + u * 8] = *(const short8*)(sp + u * 8);
      } else {
        short8 z = {0, 0, 0, 0, 0, 0, 0, 0};
#pragma unroll
        for (int u = 0; u < 4; ++u) *(short8*)&lA[ar][ap + u * 8] = z;
      }
      const unsigned short* bsp = Bt + (size_t)br * 128 + bp;
#pragma unroll
      for (int u = 0; u < 8; ++u)
        *(short8*)&lB[br][bp + u * 8] = *(const short8*)(bsp + u * 8);
    }
    __syncthreads();
#pragma unroll
    for (int ks = 0; ks < 4; ++ks) {
      short8 a = *(const short8*)&lA[wave * 16 + cl][ks * 32 + g * 8];
#pragma unroll
      for (int ct = 0; ct < 8; ++ct) {
        short8 b = *(const short8*)&lB[ct * 16 + cl][ks * 32 + g * 8];
        acc[ct] = __builtin_amdgcn_mfma_f32_16x16x32_bf16(a, b, acc[ct], 0, 0, 0);
      }
    }
  }
  __syncthreads();

  float bcol[8], gcol[8], ecol[8];
#pragma unroll
  for (int ct = 0; ct < 8; ++ct) {
    int c = ct * 16 + cl;
    bcol[ct] = bias[c]; gcol[ct] = gam[c]; ecol[ct] = bet[c];
  }
  float v[8][4];
  float s1[4] = {0.f, 0.f, 0.f, 0.f}, s2[4] = {0.f, 0.f, 0.f, 0.f};
#pragma unroll
  for (int ct = 0; ct < 8; ++ct)
#pragma unroll
    for (int r = 0; r < 4; ++r) {
      float t = acc[ct][r] + bcol[ct];
      v[ct][r] = t;
      s1[r] += t; s2[r] += t * t;
    }
#pragma unroll
  for (int m = 1; m <= 8; m <<= 1)
#pragma unroll
    for (int r = 0; r < 4; ++r) { s1[r] += __shfl_xor(s1[r], m); s2[r] += __shfl_xor(s2[r], m); }

#pragma unroll
  for (int r = 0; r < 4; ++r) {
    float mean = s1[r] * (1.f / 128.f);
    float var = s2[r] * (1.f / 128.f) - mean * mean;
    float rstd = rsqrtf(var + EPSV);
    int grow = rowBase + wave * 16 + g * 4 + r;
    if (grow < nN) {
      float o8v[8];
      float rmin = 1e30f, rmax = -1e30f;
#pragma unroll
      for (int ct = 0; ct < 8; ++ct) {
        int c = ct * 16 + cl;
        float o = fmaxf((v[ct][r] - mean) * rstd * gcol[ct] + ecol[ct], 0.f)
                  + b2f(hin16[(size_t)grow * 128 + c]);
        o8v[ct] = o;
        rmin = fminf(rmin, o); rmax = fmaxf(rmax, o);
        hout16[(size_t)grow * 128 + c] = f2b(o);
      }
      if (quant) {
#pragma unroll
        for (int m = 1; m <= 8; m <<= 1) {
          rmin = fminf(rmin, __shfl_xor(rmin, m));
          rmax = fmaxf(rmax, __shfl_xor(rmax, m));
        }
        float scale = (rmax - rmin) * (1.f / 255.f);
        float invq = (rmax > rmin) ? 255.f / (rmax - rmin) : 0.f;
#pragma unroll
        for (int ct = 0; ct < 8; ++ct) {
          int c = ct * 16 + cl;
          hout8[(size_t)grow * 128 + c] = (unsigned char)(int)rintf((o8v[ct] - rmin) * invq);
        }
        if (cl == 0) hmeta_o[grow] = make_float2(scale, rmin);
      }
    }
  }
}

// ---------------------------------------------------------------- GAT GEMM (MFMA) + logits
// G8[:, y*128..] = quant8(h @ Wg[half y]); logits (f32, exact) for heads 2y,2y+1
__global__ __launch_bounds__(256)
void k_gatgemm(const unsigned short* __restrict__ h16, const unsigned short* __restrict__ WgT,
               const float* __restrict__ atts, const float* __restrict__ attd,
               unsigned char* __restrict__ G8, float2* __restrict__ Gmeta,
               float* __restrict__ as_, float* __restrict__ ad_, int nN) {
  __shared__ unsigned short lA[64][136];
  __shared__ unsigned short lB[128][136];
  int tid = threadIdx.x;
  int wave = tid >> 6, lane = tid & 63;
  int cl = lane & 15, g = lane >> 4;
  int rowBase = blockIdx.x * 64;
  int y = blockIdx.y;
  f32x4 acc[8];
#pragma unroll
  for (int ct = 0; ct < 8; ++ct) acc[ct] = (f32x4){0.f, 0.f, 0.f, 0.f};

  int ar = tid >> 2, ap = (tid & 3) * 32;
  int br = tid >> 1, bp = (tid & 1) * 64;
  {
    int grow = rowBase + ar;
    if (grow < nN) {
      const unsigned short* sp = h16 + (size_t)grow * 128 + ap;
#pragma unroll
      for (int u = 0; u < 4; ++u)
        *(short8*)&lA[ar][ap + u * 8] = *(const short8*)(sp + u * 8);
    } else {
      short8 z = {0, 0, 0, 0, 0, 0, 0, 0};
#pragma unroll
      for (int u = 0; u < 4; ++u) *(short8*)&lA[ar][ap + u * 8] = z;
    }
    const unsigned short* bsp = WgT + (size_t)(y * 128 + br) * 128 + bp;
#pragma unroll
    for (int u = 0; u < 8; ++u)
      *(short8*)&lB[br][bp + u * 8] = *(const short8*)(bsp + u * 8);
  }
  __syncthreads();
#pragma unroll
  for (int ks = 0; ks < 4; ++ks) {
    short8 a = *(const short8*)&lA[wave * 16 + cl][ks * 32 + g * 8];
#pragma unroll
    for (int ct = 0; ct < 8; ++ct) {
      short8 b = *(const short8*)&lB[ct * 16 + cl][ks * 32 + g * 8];
      acc[ct] = __builtin_amdgcn_mfma_f32_16x16x32_bf16(a, b, acc[ct], 0, 0, 0);
    }
  }

  float atr[8], adr[8];
#pragma unroll
  for (int ct = 0; ct < 8; ++ct) {
    int h = y * 2 + (ct >> 2);
    int w = (ct & 3) * 16 + cl;
    atr[ct] = atts[h * 64 + w];
    adr[ct] = attd[h * 64 + w];
  }
  float ps[2][4], pd[2][4];
#pragma unroll
  for (int hh = 0; hh < 2; ++hh)
#pragma unroll
    for (int r = 0; r < 4; ++r) { ps[hh][r] = 0.f; pd[hh][r] = 0.f; }

#pragma unroll
  for (int r = 0; r < 4; ++r) {
    int grow = rowBase + wave * 16 + g * 4 + r;
    // row min/max (uniform across cl group; OOB rows compute garbage, never written)
    float rmin = 1e30f, rmax = -1e30f;
#pragma unroll
    for (int ct = 0; ct < 8; ++ct) {
      rmin = fminf(rmin, acc[ct][r]); rmax = fmaxf(rmax, acc[ct][r]);
    }
#pragma unroll
    for (int m = 1; m <= 8; m <<= 1) {
      rmin = fminf(rmin, __shfl_xor(rmin, m));
      rmax = fmaxf(rmax, __shfl_xor(rmax, m));
    }
    float scale = (rmax - rmin) * (1.f / 255.f);
    float invq = (rmax > rmin) ? 255.f / (rmax - rmin) : 0.f;
    if (grow < nN) {
      unsigned char* op = G8 + (size_t)grow * 256 + y * 128 + cl;
#pragma unroll
      for (int ct = 0; ct < 8; ++ct)
        op[ct * 16] = (unsigned char)(int)rintf((acc[ct][r] - rmin) * invq);
      if (cl == 0) Gmeta[grow * 2 + y] = make_float2(scale, rmin);
    }
#pragma unroll
    for (int ct = 0; ct < 8; ++ct) {
      ps[ct >> 2][r] = fmaf(acc[ct][r], atr[ct], ps[ct >> 2][r]);
      pd[ct >> 2][r] = fmaf(acc[ct][r], adr[ct], pd[ct >> 2][r]);
    }
  }
#pragma unroll
  for (int m = 1; m <= 8; m <<= 1)
#pragma unroll
    for (int hh = 0; hh < 2; ++hh)
#pragma unroll
      for (int r = 0; r < 4; ++r) {
        ps[hh][r] += __shfl_xor(ps[hh][r], m);
        pd[hh][r] += __shfl_xor(pd[hh][r], m);
      }
  if (cl == 0) {
#pragma unroll
    for (int r = 0; r < 4; ++r) {
      int grow = rowBase + wave * 16 + g * 4 + r;
      if (grow < nN) {
#pragma unroll
        for (int hh = 0; hh < 2; ++hh) {
          as_[grow * 4 + y * 2 + hh] = ps[hh][r];
          ad_[grow * 4 + y * 2 + hh] = pd[hh][r];
        }
      }
    }
  }
}

// ---------------------------------------------------------------- fused GAT gather + LN (uint8 G)
// 32 lanes/node, 8 feats/lane (uchar8); head=sub>>3, y-half=sub>>4; x4 banks
__global__ void k_gat(const unsigned char* __restrict__ G8, const float2* __restrict__ Gmeta,
                      const int* __restrict__ rowptr, const int* __restrict__ cnt,
                      const int* __restrict__ eSrc,
                      const float* __restrict__ as_, const float* __restrict__ ad_,
                      const float* __restrict__ bg, const float* __restrict__ g3,
                      const float* __restrict__ be3, float* __restrict__ out, int nN) {
  int t = blockIdx.x * 256 + threadIdx.x;
  int n = t >> 5;
  if (n >= nN) return;
  int sub = t & 31;
  int h = sub >> 3;
  int yy = sub >> 4;
  int fo = sub * 8;  // byte/col base in [0,256)
  float adn = ad_[n * 4 + h];

  // self loop -> bank 0
  float e0 = as_[n * 4 + h] + adn;
  e0 = fmaxf(e0, 0.2f * e0);
  float w = __expf(e0);
  float2 mts = Gmeta[n * 2 + yy];
  uint2 p = *(const uint2*)(G8 + (size_t)n * 256 + fo);
  float ws = w * mts.x;
  float a0[8], a1[8], a2[8], a3[8];
#pragma unroll
  for (int j = 0; j < 4; ++j) {
    a0[j] = ws * ub(p.x, j);
    a0[j + 4] = ws * ub(p.y, j);
    a1[j] = 0.f; a1[j + 4] = 0.f;
    a2[j] = 0.f; a2[j + 4] = 0.f;
    a3[j] = 0.f; a3[j + 4] = 0.f;
  }
  float m0 = w * mts.y, m1 = 0.f, m2 = 0.f, m3 = 0.f;
  float d0 = w, d1 = 0.f, d2 = 0.f, d3 = 0.f;

  int beg = rowptr[n], c = cnt[n];
  int i = 0;
  for (; i + 4 <= c; i += 4) {
    int s0 = eSrc[beg + i], s1i = eSrc[beg + i + 1];
    int s2i = eSrc[beg + i + 2], s3i = eSrc[beg + i + 3];
    float ev0 = as_[s0 * 4 + h] + adn;
    float ev1 = as_[s1i * 4 + h] + adn;
    float ev2 = as_[s2i * 4 + h] + adn;
    float ev3 = as_[s3i * 4 + h] + adn;
    ev0 = fmaxf(ev0, 0.2f * ev0); ev1 = fmaxf(ev1, 0.2f * ev1);
    ev2 = fmaxf(ev2, 0.2f * ev2); ev3 = fmaxf(ev3, 0.2f * ev3);
    float w0 = __expf(ev0), w1 = __expf(ev1), w2 = __expf(ev2), w3 = __expf(ev3);
    float2 t0 = Gmeta[s0 * 2 + yy], t1 = Gmeta[s1i * 2 + yy];
    float2 t2 = Gmeta[s2i * 2 + yy], t3 = Gmeta[s3i * 2 + yy];
    uint2 p0 = *(const uint2*)(G8 + (size_t)s0 * 256 + fo);
    uint2 p1 = *(const uint2*)(G8 + (size_t)s1i * 256 + fo);
    uint2 p2 = *(const uint2*)(G8 + (size_t)s2i * 256 + fo);
    uint2 p3 = *(const uint2*)(G8 + (size_t)s3i * 256 + fo);
    float ws0 = w0 * t0.x, ws1 = w1 * t1.x, ws2 = w2 * t2.x, ws3 = w3 * t3.x;
#pragma unroll
    for (int j = 0; j < 4; ++j) {
      a0[j] = fmaf(ws0, ub(p0.x, j), a0[j]);
      a1[j] = fmaf(ws1, ub(p1.x, j), a1[j]);
      a2[j] = fmaf(ws2, ub(p2.x, j), a2[j]);
      a3[j] = fmaf(ws3, ub(p3.x, j), a3[j]);
      a0[j + 4] = fmaf(ws0, ub(p0.y, j), a0[j + 4]);
      a1[j + 4] = fmaf(ws1, ub(p1.y, j), a1[j + 4]);
      a2[j + 4] = fmaf(ws2, ub(p2.y, j), a2[j + 4]);
      a3[j + 4] = fmaf(ws3, ub(p3.y, j), a3[j + 4]);
    }
    m0 = fmaf(w0, t0.y, m0); m1 = fmaf(w1, t1.y, m1);
    m2 = fmaf(w2, t2.y, m2); m3 = fmaf(w3, t3.y, m3);
    d0 += w0; d1 += w1; d2 += w2; d3 += w3;
  }
  for (; i < c; ++i) {
    int s = eSrc[beg + i];
    float ev = as_[s * 4 + h] + adn;
    ev = fmaxf(ev, 0.2f * ev);
    w = __expf(ev);
    float2 tm = Gmeta[s * 2 + yy];
    p = *(const uint2*)(G8 + (size_t)s * 256 + fo);
    float wsx = w * tm.x;
#pragma unroll
    for (int j = 0; j < 4; ++j) {
      a0[j] = fmaf(wsx, ub(p.x, j), a0[j]);
      a0[j + 4] = fmaf(wsx, ub(p.y, j), a0[j + 4]);
    }
    m0 = fmaf(w, tm.y, m0);
    d0 += w;
  }

  float den = (d0 + d1) + (d2 + d3);
  float mm = (m0 + m1) + (m2 + m3);
  float inv = 1.f / den;
  float a[8];
#pragma unroll
  for (int j = 0; j < 8; ++j)
    a[j] = (((a0[j] + a1[j]) + (a2[j] + a3[j])) + mm) * inv;

  // head-mean over lane bits 3,4
#pragma unroll
  for (int j = 0; j < 8; ++j) {
    a[j] += __shfl_xor(a[j], 8);
    a[j] += __shfl_xor(a[j], 16);
  }
  int fb = (sub & 7) * 8;
  float v[8];
  float s1 = 0.f, s2 = 0.f;
#pragma unroll
  for (int j = 0; j < 8; ++j) {
    v[j] = a[j] * 0.25f + bg[fb + j];
    s1 += v[j]; s2 += v[j] * v[j];
  }
#pragma unroll
  for (int m = 1; m <= 4; m <<= 1) { s1 += __shfl_xor(s1, m); s2 += __shfl_xor(s2, m); }
  float mean = s1 * (1.f / 64.f);
  float var = s2 * (1.f / 64.f) - mean * mean;
  float rstd = rsqrtf(var + EPSV);
  if (sub < 8) {
    float* o = out + (size_t)n * 64 + fb;
    float4 o1, o2;
    o1.x = (v[0] - mean) * rstd * g3[fb + 0] + be3[fb + 0];
    o1.y = (v[1] - mean) * rstd * g3[fb + 1] + be3[fb + 1];
    o1.z = (v[2] - mean) * rstd * g3[fb + 2] + be3[fb + 2];
    o1.w = (v[3] - mean) * rstd * g3[fb + 3] + be3[fb + 3];
    o2.x = (v[4] - mean) * rstd * g3[fb + 4] + be3[fb + 4];
    o2.y = (v[5] - mean) * rstd * g3[fb + 5] + be3[fb + 5];
    o2.z = (v[6] - mean) * rstd * g3[fb + 6] + be3[fb + 6];
    o2.w = (v[7] - mean) * rstd * g3[fb + 7] + be3[fb + 7];
    *(float4*)o = o1;
    *(float4*)(o + 4) = o2;
  }
}

// ================================================================ launch
extern "C" void kernel_launch(void* const* d_in, const int* in_sizes, int n_in,
                              void* d_out, int out_size, void* d_ws, size_t ws_size,
                              hipStream_t stream) {
  const float* x    = (const float*)d_in[0];
  const int*   edge = (const int*)d_in[1];
  const float* W_in = (const float*)d_in[2];
  const float* b_in = (const float*)d_in[3];
  const float* W1_l = (const float*)d_in[4];
  const float* b1   = (const float*)d_in[5];
  const float* W1_r = (const float*)d_in[6];
  const float* g1   = (const float*)d_in[7];
  const float* be1  = (const float*)d_in[8];
  const float* W2_l = (const float*)d_in[9];
  const float* b2   = (const float*)d_in[10];
  const float* W2_r = (const float*)d_in[11];
  const float* g2   = (const float*)d_in[12];
  const float* be2  = (const float*)d_in[13];
  const float* W_g  = (const float*)d_in[14];
  const float* atts = (const float*)d_in[15];
  const float* attd = (const float*)d_in[16];
  const float* b_g  = (const float*)d_in[17];
  const float* g3   = (const float*)d_in[18];
  const float* be3  = (const float*)d_in[19];

  const int nN = in_sizes[0] / 14;
  const int E_ = in_sizes[1] / 2;
  const int* src = edge;
  const int* dst = edge + E_;

  char* W = (char*)d_ws;
  unsigned short* hA16  = (unsigned short*)W; W += (size_t)nN * 128 * 2;
  unsigned short* hB16  = (unsigned short*)W; W += (size_t)nN * 128 * 2;
  unsigned short* agg16 = (unsigned short*)W; W += (size_t)nN * 128 * 2;
  unsigned short* WlT   = (unsigned short*)W; W += 16384 * 2;
  unsigned short* WrT   = (unsigned short*)W; W += 16384 * 2;
  unsigned short* WgT   = (unsigned short*)W; W += 32768 * 2;
  float* AS_ = (float*)W;                W += (size_t)nN * 4 * 4;
  float* AD_ = (float*)W;                W += (size_t)nN * 4 * 4;
  float2* metaA = (float2*)W;            W += (size_t)nN * 8;
  float2* metaB = (float2*)W;            W += (size_t)nN * 8;
  float2* Gmeta = (float2*)W;            W += (size_t)nN * 2 * 8;
  int* cntI   = (int*)W;                 W += (size_t)nN * 4;
  int* rowptr = (int*)W;                 W += (size_t)nN * 4;
  int* cursor = (int*)W;                 W += (size_t)nN * 4;
  int* incl   = (int*)W;                 W += (size_t)nN * 4;
  int* bsum   = (int*)W;                 W += 1024 * 4;
  int* eSrc   = (int*)W;                 W += (size_t)E_ * 4;
  unsigned char* h8A = (unsigned char*)W; W += (size_t)nN * 128;
  unsigned char* h8B = (unsigned char*)W; W += (size_t)nN * 128;
  unsigned char* G8  = (unsigned char*)W; W += (size_t)nN * 256;

  const int SB = (nN + 255) / 256;  // 196 for N=50000 (must be <=256)
  const int NB = (nN + 63) / 64;

  hipMemsetAsync(cntI, 0, (size_t)nN * sizeof(int), stream);
  hipMemsetAsync(cursor, 0, (size_t)nN * sizeof(int), stream);

  // CSR by dst
  k_count_int<<<(E_ + 255) / 256, 256, 0, stream>>>(dst, cntI, E_);
  k_scan1<<<SB, 256, 0, stream>>>(cntI, incl, bsum, nN);
  k_scan2<<<1, 256, 0, stream>>>(bsum, SB);
  k_scan3<<<SB, 256, 0, stream>>>(incl, bsum, cntI, rowptr, nN);
  k_fill<<<(E_ + 255) / 256, 256, 0, stream>>>(src, dst, rowptr, cursor, eSrc, E_);

  // weight prep + input projection
  k_prep3<<<256, 256, 0, stream>>>(W1_l, W1_r, W_g, WlT, WrT, WgT);
  k_proj<<<(nN * 64 + 255) / 256, 256, 0, stream>>>(x, W_in, b_in, hA16, h8A, metaA, nN);

  // SAGE layer 1: hA -> hB  (gather reads uint8 A; mfma writes bf16 B + uint8 B)
  k_sage_gather8<<<(nN * 16 + 255) / 256, 256, 0, stream>>>(h8A, metaA, rowptr, cntI, eSrc, agg16, nN);
  k_sage_mfma<<<NB, 256, 0, stream>>>(agg16, hA16, WlT, WrT, b1, g1, be1, hB16, h8B, metaB, 1, nN);

  // SAGE layer 2: hB -> hA  (no uint8 output needed; hA16 feeds GEMM only)
  k_prep2<<<128, 256, 0, stream>>>(W2_l, W2_r, WlT, WrT);
  k_sage_gather8<<<(nN * 16 + 255) / 256, 256, 0, stream>>>(h8B, metaB, rowptr, cntI, eSrc, agg16, nN);
  k_sage_mfma<<<NB, 256, 0, stream>>>(agg16, hB16, WlT, WrT, b2, g2, be2, hA16, h8A, metaA, 0, nN);

  // GAT: hA16 -> G8(+meta,+logits) -> out
  k_gatgemm<<<dim3(NB, 2), 256, 0, stream>>>(hA16, WgT, atts, attd, G8, Gmeta, AS_, AD_, nN);
  k_gat<<<(nN * 32 + 255) / 256, 256, 0, stream>>>(G8, Gmeta, rowptr, cntI, eSrc, AS_, AD_, b_g, g3, be3, (float*)d_out, nN);
}